// Round 12
// baseline (2605.223 us; speedup 1.0000x reference)
//
#include <hip/hip_runtime.h>
#include <math.h>

// ---------------------------------------------------------------------------
// Associator forward. GEMMs: A-side fp16 (hi plane only), B-side split-fp16
// (hi+lo), fp32 acc -> out = Ah*(Bh+Bl): 2 MFMA per k-pair, B exact.
// Layouts: activations are [C][Ncols] row-major fp32.
//   trk cols: 16384 (track*16+t); GNN combined cols: 5120 = [tr: b*256+n | 1024 + det: b*1024+m]
// ALL GEMMs use the 64x128-tile kernel (R11): R10 counters showed the
// 128x128 fuser GEMMs at 256 blocks = 1 block/CU, Occ 9%, MfmaUtil 6% ->
// grid-starved. 64-row tiles double the grid (2-6 blocks/CU, LDS 24KB).
// A planes staged via global_load_lds (16B DMA) into LINEAR LDS; fragment
// reads XOR-swizzled.
// attn2: flash SPLIT-K (S=4) + lo-plane drop (Q split, K/P/V hi-only).
// Sinkhorn: fp32, 60 iters x 2 micro-launches (launch-bound; persistent
// barrier 20us/barrier = 2x worse R5; fp16 Z0 = null R7).
// ---------------------------------------------------------------------------

#define NCT 16384
#define NCD 4096
#define NCB 5120
#define ZROW 257
#define ZCOL 1025
#define ZBAT (ZROW*ZCOL)   // 263425

#define SINK_IT 60

#define NORM_C  (-7.1546153569f)   // -log(1280)
#define LOG_NS  (6.9314718056f)    // log(1024)
#define LOG_MS  (5.5451774445f)    // log(256)
#define LOG_TOT (7.1546153569f)    // +log(1280)

typedef _Float16 f16x8 __attribute__((ext_vector_type(8)));
typedef _Float16 f16x4 __attribute__((ext_vector_type(4)));
typedef float f32x4 __attribute__((ext_vector_type(4)));

#define APAD 40   // LDS row stride in halves for B tiles (80 B; 2-way banks)

// 16B global->LDS stage. DMA path: per-lane global addr g, wave-uniform LDS
// base; HW places lane i at base + 16i. Fallback reproduces the placement.
__device__ __forceinline__ void stage16(const _Float16* g, _Float16* ldsbase, int lane)
{
#if __has_builtin(__builtin_amdgcn_global_load_lds)
    __builtin_amdgcn_global_load_lds(
        (const __attribute__((address_space(1))) unsigned int*)(const void*)g,
        (__attribute__((address_space(3))) unsigned int*)(void*)ldsbase, 16, 0, 0);
#else
    *(f16x8*)(ldsbase + lane * 8) = *(const f16x8*)g;
#endif
}

// ---------------- GEMM 64x128 tile (ALL gemms; A-hi plane) -----------------
// out = [W0|W1] @ [X0;X1] + bias (+res) (relu?). A-side from fp16 hi plane:
// k<C0 from Ph0 (stride S0 halves), k>=C0 from Ph1 (stride S1).
// C0%32==0 so a 32-wide k-tile never straddles.
__global__ __launch_bounds__(256) void gemm64p_kernel(
    const _Float16* __restrict__ Ph0, const _Float16* __restrict__ Pl0, int S0,
    const _Float16* __restrict__ Ph1, const _Float16* __restrict__ Pl1, int S1,
    const float* __restrict__ X0, const float* __restrict__ X1,
    const float* __restrict__ bias, const float* __restrict__ res,
    float* __restrict__ out,
    int O, int C, int C0, int N, int Nr, int No, int relu)
{
    __shared__ _Float16 Ah[64][32];
    __shared__ _Float16 Bh[128][APAD], Bl[128][APAD];
    const int tid = threadIdx.x;
    const int n0 = blockIdx.x * 128, m0 = blockIdx.y * 64;
    const int wave = tid >> 6, lane = tid & 63;
    const int wo = (wave >> 1) * 32, wn = (wave & 1) * 64;
    const int lm = lane & 15, lq = lane >> 4;
    // A DMA: lane i -> LDS row r0+(i>>2), 16B slot (i&3). Swizzle: slot s of
    // row R holds k-chunk s ^ ((R>>1)&3)  =>  lane fetches chunk
    // (i&3)^((i>>3)&3); read of k-chunk lq at row R uses slot lq^((R>>1)&3).
    const int sar = lane >> 2;
    const int sakx = ((lane & 3) ^ ((lane >> 3) & 3)) * 8;
    const int asw = (lq ^ ((lm >> 1) & 3)) * 8;   // swizzled A-frag k-offset
    const int bkg = tid & 7, bng = tid >> 3;

    f32x4 acc[2][4] = {};

    for (int kb = 0; kb < C; kb += 32) {
        float4 xv[4];
        #pragma unroll
        for (int r = 0; r < 4; ++r) {
            const int krow = kb + bkg * 4 + r;
            const float* xs = (krow < C0) ? X0 + (size_t)krow * N
                                          : X1 + (size_t)(krow - C0) * N;
            xv[r] = *(const float4*)(xs + n0 + bng * 4);
        }
        const bool s0 = (kb < C0);
        const _Float16* ph = s0 ? Ph0 : Ph1;
        const int S = s0 ? S0 : S1;
        const int kc = s0 ? kb : kb - C0;
        __syncthreads();
        // ---- A: 16B DMA of hi plane (one instr per wave) ----
        {
            const int r0 = wave * 16;
            const size_t go = (size_t)(m0 + r0 + sar) * S + kc + sakx;
            stage16(ph + go, &Ah[r0][0], lane);
        }
        // ---- B: convert + transposed store ----
        #pragma unroll
        for (int j = 0; j < 4; ++j) {
            _Float16 hb[4], lb[4];
            #pragma unroll
            for (int r = 0; r < 4; ++r) {
                const float x = ((const float*)&xv[r])[j];
                const _Float16 h = (_Float16)x;
                hb[r] = h;
                lb[r] = (_Float16)(x - (float)h);
            }
            *(f16x4*)&Bh[bng * 4 + j][bkg * 4] = *(const f16x4*)&hb[0];
            *(f16x4*)&Bl[bng * 4 + j][bkg * 4] = *(const f16x4*)&lb[0];
        }
        __syncthreads();
        f16x8 bh[4], bl[4];
        #pragma unroll
        for (int t = 0; t < 4; ++t) {
            bh[t] = *(const f16x8*)&Bh[wn + t * 16 + lm][lq * 8];
            bl[t] = *(const f16x8*)&Bl[wn + t * 16 + lm][lq * 8];
        }
        #pragma unroll
        for (int mt = 0; mt < 2; ++mt) {
            const f16x8 ah = *(const f16x8*)&Ah[wo + mt * 16 + lm][asw];
            #pragma unroll
            for (int nt = 0; nt < 4; ++nt) {
                acc[mt][nt] = __builtin_amdgcn_mfma_f32_16x16x32_f16(ah, bh[nt], acc[mt][nt], 0, 0, 0);
                acc[mt][nt] = __builtin_amdgcn_mfma_f32_16x16x32_f16(ah, bl[nt], acc[mt][nt], 0, 0, 0);
            }
        }
    }
    #pragma unroll
    for (int mt = 0; mt < 2; ++mt) {
        #pragma unroll
        for (int rg = 0; rg < 4; ++rg) {
            const int o = m0 + wo + mt * 16 + lq * 4 + rg;
            const float bs = bias[o];
            #pragma unroll
            for (int nt = 0; nt < 4; ++nt) {
                const int n = n0 + wn + nt * 16 + lm;
                float v = acc[mt][nt][rg] + bs;
                if (res) v += res[(size_t)o * Nr + n];
                if (relu) v = fmaxf(v, 0.f);
                out[(size_t)o * No + n] = v;
            }
        }
    }
}

// ---------------- merged weight split: fp32 -> fp16 hi/lo planes -----------
__global__ void split_multi_kernel(
    const float* __restrict__ s0, _Float16* __restrict__ h0, _Float16* __restrict__ l0, int c0, int st0,
    const float* __restrict__ s1, _Float16* __restrict__ h1, _Float16* __restrict__ l1, int c1, int st1,
    const float* __restrict__ s2, _Float16* __restrict__ h2, _Float16* __restrict__ l2, int c2, int st2,
    const float* __restrict__ s3, _Float16* __restrict__ h3, _Float16* __restrict__ l3, int c3, int st3,
    const float* __restrict__ s4, _Float16* __restrict__ h4, _Float16* __restrict__ l4, int c4, int st4)
{
    int b = blockIdx.x;
    const float* s; _Float16* h; _Float16* l; int st;
    if      (b < c0) {               s = s0; h = h0; l = l0; st = st0; }
    else if (b < c1) { b -= c0;      s = s1; h = h1; l = l1; st = st1; }
    else if (b < c2) { b -= c1;      s = s2; h = h2; l = l2; st = st2; }
    else if (b < c3) { b -= c2;      s = s3; h = h3; l = l3; st = st3; }
    else             { b -= c3;      s = s4; h = h4; l = l4; st = st4; }
    const int i = b * 256 + threadIdx.x;
    const float x = st ? s[(size_t)(i >> 8) * st + (i & 255)] : s[i];
    const _Float16 hh = (_Float16)x;
    h[i] = hh;
    l[i] = (_Float16)(x - (float)hh);
}

// ---------------- batched Wf = m1wB @ mw, fp16-plane out -------------------
__global__ __launch_bounds__(256) void fusewh_kernel(
    const float* __restrict__ m1w_base, const float* __restrict__ mw_base,
    _Float16* __restrict__ wfh_base, _Float16* __restrict__ wfl_base)
{
    const int z = blockIdx.z;
    const float* A = m1w_base + (size_t)z * 262144 + 256;
    const float* B = mw_base + (size_t)z * 65536;
    _Float16* oh = wfh_base + (size_t)z * 131072;
    _Float16* ol = wfl_base + (size_t)z * 131072;
    __shared__ _Float16 Ah[64][APAD], Al[64][APAD];
    __shared__ _Float16 Bh[128][APAD], Bl[128][APAD];
    const int tid = threadIdx.x;
    const int n0 = blockIdx.x * 128, m0 = blockIdx.y * 64;
    const int wave = tid >> 6, lane = tid & 63;
    const int wo = (wave >> 1) * 32, wn = (wave & 1) * 64;
    const int lm = lane & 15, lq = lane >> 4;
    const int ar = tid >> 2, ak8 = (tid & 3) << 3;
    const int bkg = tid & 7, bng = tid >> 3;

    f32x4 acc[2][4] = {};
    for (int kb = 0; kb < 256; kb += 32) {
        float4 av[2];
        const float* wp = A + (size_t)(m0 + ar) * 512 + kb + ak8;
        av[0] = *(const float4*)(wp);
        av[1] = *(const float4*)(wp + 4);
        float4 xv[4];
        #pragma unroll
        for (int r = 0; r < 4; ++r)
            xv[r] = *(const float4*)(B + (size_t)(kb + bkg * 4 + r) * 256 + n0 + bng * 4);
        __syncthreads();
        {
            _Float16 hbuf[8], lbuf[8];
            #pragma unroll
            for (int q = 0; q < 2; ++q) {
                const float* f = (const float*)&av[q];
                #pragma unroll
                for (int c = 0; c < 4; ++c) {
                    const float x = f[c];
                    const _Float16 h = (_Float16)x;
                    hbuf[q * 4 + c] = h;
                    lbuf[q * 4 + c] = (_Float16)(x - (float)h);
                }
            }
            *(f16x8*)&Ah[ar][ak8] = *(const f16x8*)&hbuf[0];
            *(f16x8*)&Al[ar][ak8] = *(const f16x8*)&lbuf[0];
        }
        #pragma unroll
        for (int j = 0; j < 4; ++j) {
            _Float16 hb[4], lb[4];
            #pragma unroll
            for (int r = 0; r < 4; ++r) {
                const float x = ((const float*)&xv[r])[j];
                const _Float16 h = (_Float16)x;
                hb[r] = h;
                lb[r] = (_Float16)(x - (float)h);
            }
            *(f16x4*)&Bh[bng * 4 + j][bkg * 4] = *(const f16x4*)&hb[0];
            *(f16x4*)&Bl[bng * 4 + j][bkg * 4] = *(const f16x4*)&lb[0];
        }
        __syncthreads();
        f16x8 bh[4], bl[4];
        #pragma unroll
        for (int t = 0; t < 4; ++t) {
            bh[t] = *(const f16x8*)&Bh[wn + t * 16 + lm][lq * 8];
            bl[t] = *(const f16x8*)&Bl[wn + t * 16 + lm][lq * 8];
        }
        #pragma unroll
        for (int mt = 0; mt < 2; ++mt) {
            const f16x8 ah = *(const f16x8*)&Ah[wo + mt * 16 + lm][lq * 8];
            const f16x8 al = *(const f16x8*)&Al[wo + mt * 16 + lm][lq * 8];
            #pragma unroll
            for (int nt = 0; nt < 4; ++nt) {
                acc[mt][nt] = __builtin_amdgcn_mfma_f32_16x16x32_f16(ah, bh[nt], acc[mt][nt], 0, 0, 0);
                acc[mt][nt] = __builtin_amdgcn_mfma_f32_16x16x32_f16(ah, bl[nt], acc[mt][nt], 0, 0, 0);
                acc[mt][nt] = __builtin_amdgcn_mfma_f32_16x16x32_f16(al, bh[nt], acc[mt][nt], 0, 0, 0);
            }
        }
    }
    #pragma unroll
    for (int mt = 0; mt < 2; ++mt)
        #pragma unroll
        for (int rg = 0; rg < 4; ++rg) {
            const int o = m0 + wo + mt * 16 + lq * 4 + rg;
            #pragma unroll
            for (int nt = 0; nt < 4; ++nt) {
                const float v = acc[mt][nt][rg];
                const _Float16 hh = (_Float16)v;
                oh[(size_t)o * 256 + n0 + wn + nt * 16 + lm] = hh;
                ol[(size_t)o * 256 + n0 + wn + nt * 16 + lm] = (_Float16)(v - (float)hh);
            }
        }
}

// ---------------- batched bc = m1wB @ mb + m1b -----------------------------
__global__ void fusebias_kernel(const float* __restrict__ m1w_base,
                                const float* __restrict__ mb_base,
                                const float* __restrict__ m1b_base,
                                float* __restrict__ bc_base)
{
    const int z = blockIdx.y;
    const int o = blockIdx.x * 256 + threadIdx.x;   // 0..511
    const float* A = m1w_base + (size_t)z * 262144 + (size_t)o * 512 + 256;
    const float* mb = mb_base + z * 256;
    float s = m1b_base[z * 512 + o];
    for (int c = 0; c < 256; ++c) s = fmaf(A[c], mb[c], s);
    bc_base[z * 512 + o] = s;
}

// ---------------- positional encoding (grid.y splits the 128 i's) ---------
__global__ void pe_kernel(const float* __restrict__ src, float* __restrict__ pe,
                          int N, int shift, int cstride)
{
    const int col = blockIdx.x * 256 + threadIdx.x;
    if (col >= N) return;
    const int seg = 1 << shift;
    const int i0 = blockIdx.y * 32;
    const float pos = src[(size_t)(col >> shift) * cstride + (col & (seg - 1))];
    #pragma unroll 4
    for (int i = i0; i < i0 + 32; ++i) {
        const float div = expf((float)i * -0.07195578415606394f); // -ln(10000)/128
        const float ang = pos * div;
        pe[(size_t)(2*i) * N + col]   = sinf(ang);
        pe[(size_t)(2*i+1) * N + col] = cosf(ang);
    }
}

// ---------------- input repack (drop channel 0) ---------------------------
__global__ void repack_kernel(const float* __restrict__ src, float* __restrict__ dst,
                              int N, int shift, int cstride)
{
    const int col = blockIdx.x * 256 + threadIdx.x;
    const int c = blockIdx.y;
    if (col >= N) return;
    const int seg = 1 << shift;
    dst[(size_t)c * N + col] =
        src[(size_t)(col >> shift) * cstride + (size_t)(c + 1) * seg + (col & (seg - 1))];
}

// ---------------- fuser self-attention over time (n=m=16 per track) -------
__global__ __launch_bounds__(256) void fuser_attn_kernel(
    const float* __restrict__ Qb, const float* __restrict__ Kb,
    const float* __restrict__ Vb, float* __restrict__ Ob)
{
    __shared__ float qs[256][17], ks[256][17], vs[256][17];
    __shared__ float ps[4][16][17];
    const int trk = blockIdx.x, tid = threadIdx.x;
    const int col0 = trk * 16;
    for (int idx = tid; idx < 1024; idx += 256) {
        const int r = idx >> 2, seg = (idx & 3) << 2;
        const float4 q = *(const float4*)&Qb[(size_t)r * NCT + col0 + seg];
        const float4 k = *(const float4*)&Kb[(size_t)r * NCT + col0 + seg];
        const float4 v = *(const float4*)&Vb[(size_t)r * NCT + col0 + seg];
        qs[r][seg]=q.x; qs[r][seg+1]=q.y; qs[r][seg+2]=q.z; qs[r][seg+3]=q.w;
        ks[r][seg]=k.x; ks[r][seg+1]=k.y; ks[r][seg+2]=k.z; ks[r][seg+3]=k.w;
        vs[r][seg]=v.x; vs[r][seg+1]=v.y; vs[r][seg+2]=v.z; vs[r][seg+3]=v.w;
    }
    __syncthreads();
    {
        const int g = tid >> 2, h = g >> 4, n = g & 15, mb = (tid & 3) << 2;
        float s[4] = {};
        #pragma unroll 4
        for (int hd = 0; hd < 64; ++hd) {
            const int c = hd*4 + h;
            const float q = qs[c][n];
            #pragma unroll
            for (int j = 0; j < 4; ++j) s[j] = fmaf(q, ks[c][mb + j], s[j]);
        }
        #pragma unroll
        for (int j = 0; j < 4; ++j) ps[h][n][mb + j] = s[j] * 0.125f;
    }
    __syncthreads();
    if (tid < 64) {
        const int hh = tid >> 4, nn = tid & 15;
        float mx = -INFINITY;
        for (int m = 0; m < 16; ++m) mx = fmaxf(mx, ps[hh][nn][m]);
        float sum = 0.f;
        for (int m = 0; m < 16; ++m) { const float p = expf(ps[hh][nn][m] - mx);
                                       ps[hh][nn][m] = p; sum += p; }
        const float inv = 1.f / sum;
        for (int m = 0; m < 16; ++m) ps[hh][nn][m] *= inv;
    }
    __syncthreads();
    {
        const int c = tid, hc = c & 3;
        float msg[16];
        #pragma unroll
        for (int n = 0; n < 16; ++n) {
            float a = 0.f;
            #pragma unroll
            for (int m = 0; m < 16; ++m) a = fmaf(ps[hc][n][m], vs[c][m], a);
            msg[n] = a;
        }
        __syncthreads();
        #pragma unroll
        for (int n = 0; n < 16; ++n) qs[c][n] = msg[n];
    }
    __syncthreads();
    for (int idx = tid; idx < 1024; idx += 256) {
        const int r = idx >> 2, seg = (idx & 3) << 2;
        *(float4*)&Ob[(size_t)r * NCT + col0 + seg] =
            make_float4(qs[r][seg], qs[r][seg+1], qs[r][seg+2], qs[r][seg+3]);
    }
}

// ---------------- GNN attention: fp16 MFMA flash, SPLIT-K (S=4) -----------
// grid.x = 80: nt_raw = x>>2 (LPT remap), s = x&3 -> m-tiles [s*cnt, s*cnt+cnt).
// Q split (hi+lo), K/P/V hi-only: QK 2 MFMA, PV 1 MFMA per frag pair.
// Writes unnormalized partials: PO fp16 [qt][s][64 q][64 d], PM/PL fp32.
// LDS: 2 buffers (K/P | V), Q staged through them before the loop.
__global__ __launch_bounds__(256) void attn2_kernel(
    const float* __restrict__ QKV, _Float16* __restrict__ PO,
    float* __restrict__ PM, float* __restrict__ PL, int cross)
{
    __shared__ _Float16 SH[2][64][72];
    _Float16 (*Kh)[72] = SH[0];   // K hi; P hi after QK; Q hi at start
    _Float16 (*Vh)[72] = SH[1];   // V hi; Q lo at start
    const int b = blockIdx.z, h = blockIdx.y;
    const int raw = blockIdx.x;
    const int sp = raw & 3;
    const int nt_raw = raw >> 2;
    const int nt = cross ? nt_raw : ((nt_raw < 16) ? (nt_raw + 4) : (nt_raw - 16));
    const float* Qb = QKV;
    const float* Kb = QKV + (size_t)256 * NCB;
    const float* Vb = QKV + (size_t)512 * NCB;
    int qcol, kbase, nk;
    if (nt < 4) {
        qcol = b * 256 + nt * 64;
        if (cross) { kbase = 1024 + b * 1024; nk = 1024; }
        else       { kbase = b * 256;         nk = 256;  }
    } else {
        qcol = 1024 + b * 1024 + (nt - 4) * 64;
        if (cross) { kbase = b * 256;         nk = 256;  }
        else       { kbase = 1024 + b * 1024; nk = 1024; }
    }
    const int tid = threadIdx.x;
    const int wave = tid >> 6, lane = tid & 63;
    const int lm = lane & 15, quad = lane >> 4;
    const int dg = tid & 15, qg = tid >> 4;
    const int vd = tid >> 2, vseg = (tid & 3) * 16;
    const int vchan = vd * 4 + h;

    // ---- Q stage (hi->Kh, lo->Vh) + consume to regs ----
    {
        float4 xv[4];
        #pragma unroll
        for (int r = 0; r < 4; ++r) {
            const int chan = (dg * 4 + r) * 4 + h;
            xv[r] = *(const float4*)&Qb[(size_t)chan * NCB + qcol + qg * 4];
        }
        #pragma unroll
        for (int j = 0; j < 4; ++j) {
            _Float16 hb[4], lb[4];
            #pragma unroll
            for (int r = 0; r < 4; ++r) {
                const float x = ((const float*)&xv[r])[j];
                const _Float16 hh = (_Float16)x;
                hb[r] = hh; lb[r] = (_Float16)(x - (float)hh);
            }
            *(f16x4*)&Kh[qg * 4 + j][dg * 4] = *(const f16x4*)hb;
            *(f16x4*)&Vh[qg * 4 + j][dg * 4] = *(const f16x4*)lb;
        }
    }
    __syncthreads();
    f16x8 qh[2], ql[2];
    #pragma unroll
    for (int ks = 0; ks < 2; ++ks) {
        qh[ks] = *(const f16x8*)&Kh[wave * 16 + lm][ks * 32 + quad * 8];
        ql[ks] = *(const f16x8*)&Vh[wave * 16 + lm][ks * 32 + quad * 8];
    }

    float rmax[4], rsum[4];
    #pragma unroll
    for (int r = 0; r < 4; ++r) { rmax[r] = -INFINITY; rsum[r] = 0.f; }
    f32x4 acco[4] = {};

    const int mtn = nk >> 6;
    const int cnt = mtn >> 2;       // S=4 parts
    const int mt0 = sp * cnt;
    const int mtE = mt0 + cnt;
    float4 kxv[4], vxv[4];
    {
        const int kcol = kbase + mt0 * 64;
        #pragma unroll
        for (int r = 0; r < 4; ++r) {
            const int chan = (dg * 4 + r) * 4 + h;
            kxv[r] = *(const float4*)&Kb[(size_t)chan * NCB + kcol + qg * 4];
        }
        #pragma unroll
        for (int q = 0; q < 4; ++q)
            vxv[q] = *(const float4*)&Vb[(size_t)vchan * NCB + kcol + vseg + q * 4];
    }
    for (int mt = mt0; mt < mtE; ++mt) {
        __syncthreads();   // prior tile's (or Q's) fragment reads complete
        // ---- K hi convert+store ----
        #pragma unroll
        for (int j = 0; j < 4; ++j) {
            _Float16 hb[4];
            #pragma unroll
            for (int r = 0; r < 4; ++r)
                hb[r] = (_Float16)((const float*)&kxv[r])[j];
            *(f16x4*)&Kh[qg * 4 + j][dg * 4] = *(const f16x4*)hb;
        }
        // ---- V hi convert+store ----
        {
            _Float16 vh16[16];
            #pragma unroll
            for (int q = 0; q < 4; ++q) {
                const float* f = (const float*)&vxv[q];
                #pragma unroll
                for (int c = 0; c < 4; ++c) vh16[q*4+c] = (_Float16)f[c];
            }
            *(f16x8*)&Vh[vd][vseg]     = *(const f16x8*)&vh16[0];
            *(f16x8*)&Vh[vd][vseg + 8] = *(const f16x8*)&vh16[8];
        }
        __syncthreads();
        // ---- issue next tile's loads (overlap QK+softmax+PV below) ----
        if (mt + 1 < mtE) {
            const int kcol = kbase + (mt + 1) * 64;
            #pragma unroll
            for (int r = 0; r < 4; ++r) {
                const int chan = (dg * 4 + r) * 4 + h;
                kxv[r] = *(const float4*)&Kb[(size_t)chan * NCB + kcol + qg * 4];
            }
            #pragma unroll
            for (int q = 0; q < 4; ++q)
                vxv[q] = *(const float4*)&Vb[(size_t)vchan * NCB + kcol + vseg + q * 4];
        }
        // ---- QK: full Q x K-hi (2 MFMA per frag pair) ----
        f32x4 accs[4] = {};
        #pragma unroll
        for (int t = 0; t < 4; ++t) {
            #pragma unroll
            for (int ks = 0; ks < 2; ++ks) {
                const f16x8 kh = *(const f16x8*)&Kh[t * 16 + lm][ks * 32 + quad * 8];
                accs[t] = __builtin_amdgcn_mfma_f32_16x16x32_f16(qh[ks], kh, accs[t], 0,0,0);
                accs[t] = __builtin_amdgcn_mfma_f32_16x16x32_f16(ql[ks], kh, accs[t], 0,0,0);
            }
        }
        float alpha[4];
        float psv[4][4];
        #pragma unroll
        for (int r = 0; r < 4; ++r) {
            float mx = fmaxf(fmaxf(accs[0][r], accs[1][r]),
                             fmaxf(accs[2][r], accs[3][r])) * 0.125f;
            #pragma unroll
            for (int off = 1; off < 16; off <<= 1) mx = fmaxf(mx, __shfl_xor(mx, off));
            const float mnew = fmaxf(rmax[r], mx);
            alpha[r] = expf(rmax[r] - mnew);
            rmax[r] = mnew;
            float s = 0.f;
            #pragma unroll
            for (int t = 0; t < 4; ++t) {
                const float p = expf(accs[t][r] * 0.125f - mnew);
                psv[t][r] = p; s += p;
            }
            #pragma unroll
            for (int off = 1; off < 16; off <<= 1) s += __shfl_xor(s, off);
            rsum[r] = rsum[r] * alpha[r] + s;
        }
        __syncthreads();
        // ---- P hi store (into Kh) ----
        #pragma unroll
        for (int t = 0; t < 4; ++t)
            #pragma unroll
            for (int r = 0; r < 4; ++r)
                Kh[wave * 16 + quad * 4 + r][t * 16 + lm] = (_Float16)psv[t][r];
        __syncthreads();
        #pragma unroll
        for (int td = 0; td < 4; ++td)
            #pragma unroll
            for (int r = 0; r < 4; ++r) acco[td][r] *= alpha[r];
        // ---- PV: P-hi x V-hi (1 MFMA per frag pair) ----
        #pragma unroll
        for (int ks = 0; ks < 2; ++ks) {
            const f16x8 ph = *(const f16x8*)&Kh[wave * 16 + lm][ks * 32 + quad * 8];
            #pragma unroll
            for (int td = 0; td < 4; ++td) {
                const f16x8 vh = *(const f16x8*)&Vh[td * 16 + lm][ks * 32 + quad * 8];
                acco[td] = __builtin_amdgcn_mfma_f32_16x16x32_f16(ph, vh, acco[td], 0,0,0);
            }
        }
    }
    // ---- write partials (unnormalized acc + m/l per q-row) ----
    const int qt = ((b * 4 + h) * 20 + nt);
    _Float16* po = PO + ((size_t)(qt * 4 + sp) * 64) * 64;
    #pragma unroll
    for (int td = 0; td < 4; ++td)
        #pragma unroll
        for (int r = 0; r < 4; ++r)
            po[(wave * 16 + quad * 4 + r) * 64 + td * 16 + lm] = (_Float16)acco[td][r];
    if (lm == 0) {
        #pragma unroll
        for (int r = 0; r < 4; ++r) {
            const int qrow = wave * 16 + quad * 4 + r;
            PM[(qt * 4 + sp) * 64 + qrow] = rmax[r];
            PL[(qt * 4 + sp) * 64 + qrow] = rsum[r];
        }
    }
}

// ---------------- flash merge of S=4 attn partials -> MSG -----------------
__global__ __launch_bounds__(256) void attn_merge_kernel(
    const _Float16* __restrict__ PO, const float* __restrict__ PM,
    const float* __restrict__ PL, float* __restrict__ MSG)
{
    const int b = blockIdx.z, h = blockIdx.y, nt = blockIdx.x;   // logical nt
    const int qcol = (nt < 4) ? (b * 256 + nt * 64) : (1024 + b * 1024 + (nt - 4) * 64);
    const int qt = ((b * 4 + h) * 20 + nt);
    const int tid = threadIdx.x;
    const int qp = tid & 63, cg = tid >> 6;
    float w[4];
    float mg = -INFINITY;
    #pragma unroll
    for (int s = 0; s < 4; ++s) { w[s] = PM[(qt * 4 + s) * 64 + qp]; mg = fmaxf(mg, w[s]); }
    float l = 0.f;
    #pragma unroll
    for (int s = 0; s < 4; ++s) {
        w[s] = expf(w[s] - mg);
        l += w[s] * PL[(qt * 4 + s) * 64 + qp];
    }
    const float invl = 1.f / l;
    f16x8 a0[4], a1[4];
    #pragma unroll
    for (int s = 0; s < 4; ++s) {
        const _Float16* base = PO + (((size_t)(qt * 4 + s) * 64 + qp) * 64 + cg * 16);
        a0[s] = *(const f16x8*)base;
        a1[s] = *(const f16x8*)(base + 8);
    }
    #pragma unroll
    for (int i = 0; i < 8; ++i) {
        float o = 0.f;
        #pragma unroll
        for (int s = 0; s < 4; ++s) o += w[s] * (float)a0[s][i];
        const int d = cg * 16 + i;
        MSG[(size_t)(d * 4 + h) * NCB + qcol + qp] = o * invl;
    }
    #pragma unroll
    for (int i = 0; i < 8; ++i) {
        float o = 0.f;
        #pragma unroll
        for (int s = 0; s < 4; ++s) o += w[s] * (float)a1[s][i];
        const int d = cg * 16 + 8 + i;
        MSG[(size_t)(d * 4 + h) * NCB + qcol + qp] = o * invl;
    }
}

// ---------------- mean pool over time (into combined cols [0,1024)) -------
__global__ void meanpool_kernel(const float* __restrict__ x, float* __restrict__ tr)
{
    const int trk = blockIdx.x * 256 + threadIdx.x;
    const int d = blockIdx.y;
    const float* p = x + (size_t)d * NCT + (size_t)trk * 16;
    float s = 0.f;
    #pragma unroll
    for (int t = 0; t < 16; ++t) s += p[t];
    tr[(size_t)d * NCB + trk] = s * 0.0625f;
}

// ---------------- scores = m0^T m1 / 16 into Z0 and Z0T -------------------
__global__ __launch_bounds__(256) void scores_kernel(
    const float* __restrict__ M, float* __restrict__ Z0, float* __restrict__ Z0T)
{
    __shared__ float As[8][68];
    __shared__ float Bs[8][68];
    const int bm = blockIdx.x, bn = blockIdx.y, b = blockIdx.z;
    const int tid = threadIdx.x;
    const int n0 = bn * 64, mm0 = bm * 64;
    const int tx = tid & 15, ty = tid >> 4;
    float acc[4][4] = {};
    for (int kb = 0; kb < 256; kb += 8) {
        __syncthreads();
        for (int idx = tid; idx < 512; idx += 256) {
            const int r = idx >> 6, cc = idx & 63;
            As[r][cc] = M[(size_t)(kb + r) * NCB + b * 256 + n0 + cc];
            Bs[r][cc] = M[(size_t)(kb + r) * NCB + 1024 + b * 1024 + mm0 + cc];
        }
        __syncthreads();
        #pragma unroll
        for (int kk = 0; kk < 8; ++kk) {
            float a[4], bv[4];
            #pragma unroll
            for (int i = 0; i < 4; ++i) { a[i] = As[kk][ty*4 + i]; bv[i] = Bs[kk][tx*4 + i]; }
            #pragma unroll
            for (int i = 0; i < 4; ++i)
                #pragma unroll
                for (int j = 0; j < 4; ++j) acc[i][j] = fmaf(a[i], bv[j], acc[i][j]);
        }
    }
    #pragma unroll
    for (int i = 0; i < 4; ++i)
        #pragma unroll
        for (int j = 0; j < 4; ++j) {
            const float s = acc[i][j] * 0.0625f;
            const int rr = n0 + ty*4 + i, cc = mm0 + tx*4 + j;
            Z0 [(size_t)b * ZBAT + (size_t)rr * ZCOL + cc] = s;
            Z0T[(size_t)b * ZBAT + (size_t)cc * ZROW + rr] = s;
        }
}

// ---------------- sinkhorn ------------------------------------------------
__global__ void sink_init_kernel(float* __restrict__ Z0, float* __restrict__ Z0T,
                                 float* __restrict__ v, const float* __restrict__ binp)
{
    const float alpha = binp[0];
    const int idx = blockIdx.x * 256 + threadIdx.x;
    if (idx < 4 * ZCOL) v[idx] = 0.f;
    if (idx < 4 * 1281) {
        const int b = idx / 1281, e = idx % 1281;
        if (e < 1025) Z0[(size_t)b * ZBAT + 256 * ZCOL + e] = alpha;
        else          Z0[(size_t)b * ZBAT + (size_t)(e - 1025) * ZCOL + 1024] = alpha;
    }
    if (idx < 4 * 1282) {
        const int b = idx / 1282, e = idx % 1282;
        if (e < 257) Z0T[(size_t)b * ZBAT + 1024 * ZROW + e] = alpha;
        else         Z0T[(size_t)b * ZBAT + (size_t)(e - 257) * ZROW + 256] = alpha;
    }
}

__global__ __launch_bounds__(256) void sink_u_kernel(
    const float* __restrict__ Z0, const float* __restrict__ v, float* __restrict__ u)
{
    const int w = threadIdx.x >> 6, lane = threadIdx.x & 63;
    const int row = blockIdx.x * 4 + w;          // 0..1027
    const int b = row / 257, i = row % 257;
    const float* z  = Z0 + (size_t)b * ZBAT + (size_t)i * ZCOL;
    const float* vb = v + b * ZCOL;
    float zz[17];
    float mx = -INFINITY;
    #pragma unroll
    for (int k = 0; k < 16; ++k) {
        zz[k] = z[lane + k*64] + vb[lane + k*64];
        mx = fmaxf(mx, zz[k]);
    }
    zz[16] = (lane == 0) ? (z[1024] + vb[1024]) : -INFINITY;
    mx = fmaxf(mx, zz[16]);
    #pragma unroll
    for (int off = 32; off; off >>= 1) mx = fmaxf(mx, __shfl_xor(mx, off));
    float s = 0.f;
    #pragma unroll
    for (int k = 0; k < 17; ++k) s += expf(zz[k] - mx);
    #pragma unroll
    for (int off = 32; off; off >>= 1) s += __shfl_xor(s, off);
    if (lane == 0) {
        const float lmu = (i < 256) ? NORM_C : (LOG_NS + NORM_C);
        u[b * 257 + i] = lmu - (mx + logf(s));
    }
}

__global__ __launch_bounds__(256) void sink_v_kernel(
    const float* __restrict__ Z0T, const float* __restrict__ u, float* __restrict__ v)
{
    const int w = threadIdx.x >> 6, lane = threadIdx.x & 63;
    const int row = blockIdx.x * 4 + w;          // 0..4099
    const int b = row / 1025, j = row - b * 1025;
    const float* z  = Z0T + (size_t)b * ZBAT + (size_t)j * ZROW;
    const float* ub = u + b * 257;
    float zz[5];
    float mx = -INFINITY;
    #pragma unroll
    for (int k = 0; k < 4; ++k) {
        zz[k] = z[lane + k*64] + ub[lane + k*64];
        mx = fmaxf(mx, zz[k]);
    }
    zz[4] = (lane == 0) ? (z[256] + ub[256]) : -INFINITY;
    mx = fmaxf(mx, zz[4]);
    #pragma unroll
    for (int off = 32; off; off >>= 1) mx = fmaxf(mx, __shfl_xor(mx, off));
    float s = 0.f;
    #pragma unroll
    for (int k = 0; k < 5; ++k) s += expf(zz[k] - mx);
    #pragma unroll
    for (int off = 32; off; off >>= 1) s += __shfl_xor(s, off);
    if (lane == 0) {
        const float lnu = (j < 1024) ? NORM_C : (LOG_MS + NORM_C);
        v[b * ZCOL + j] = lnu - (mx + logf(s));
    }
}

__global__ void sink_out_kernel(const float* __restrict__ Z0, const float* __restrict__ u,
                                const float* __restrict__ v, float* __restrict__ out)
{
    const int j = blockIdx.x * 256 + threadIdx.x;
    const int i = blockIdx.y, b = blockIdx.z;
    if (j < ZCOL) {
        const size_t idx = (size_t)b * ZBAT + (size_t)i * ZCOL + j;
        out[idx] = Z0[idx] + u[b * 257 + i] + v[b * ZCOL + j] + LOG_TOT;
    }
}

// ---------------------------------------------------------------------------
static inline void gemmP64(hipStream_t st,
                           const _Float16* Ph0, const _Float16* Pl0, int S0,
                           const _Float16* Ph1, const _Float16* Pl1, int S1,
                           const float* X0, const float* X1, int C0,
                           const float* bias, const float* res, int Nr,
                           float* out, int No, int O, int C, int N, int relu)
{
    dim3 g(N / 128, O / 64);
    gemm64p_kernel<<<g, 256, 0, st>>>(Ph0, Pl0, S0, Ph1, Pl1, S1, X0, X1,
                                      bias, res, out, O, C, C0, N, Nr, No, relu);
}

extern "C" void kernel_launch(void* const* d_in, const int* in_sizes, int n_in,
                              void* d_out, int out_size, void* d_ws, size_t ws_size,
                              hipStream_t stream)
{
    (void)in_sizes; (void)n_in; (void)out_size; (void)ws_size;
    const float* det_in = (const float*)d_in[0];
    const float* trk_in = (const float*)d_in[1];
    const float* enc_w1 = (const float*)d_in[2];
    const float* enc_b1 = (const float*)d_in[3];
    const float* enc_w2 = (const float*)d_in[4];
    const float* enc_b2 = (const float*)d_in[5];
    const float* fus_pw = (const float*)d_in[6];
    const float* fus_pb = (const float*)d_in[7];
    const float* fus_mw = (const float*)d_in[8];
    const float* fus_mb = (const float*)d_in[9];
    const float* fus_m1w = (const float*)d_in[10];
    const float* fus_m1b = (const float*)d_in[11];
    const float* fus_m2w = (const float*)d_in[12];
    const float* fus_m2b = (const float*)d_in[13];
    const float* gnn_pw = (const float*)d_in[14];
    const float* gnn_pb = (const float*)d_in[15];
    const float* gnn_mw = (const float*)d_in[16];
    const float* gnn_mb = (const float*)d_in[17];
    const float* gnn_m1w = (const float*)d_in[18];
    const float* gnn_m1b = (const float*)d_in[19];
    const float* gnn_m2w = (const float*)d_in[20];
    const float* gnn_m2b = (const float*)d_in[21];
    const float* final_w = (const float*)d_in[22];
    const float* final_b = (const float*)d_in[23];
    const float* bin_sc  = (const float*)d_in[24];
    float* out = (float*)d_out;

    float* ws = (float*)d_ws;
    float* XF   = ws;                      // 4,194,304  fuser state x [256][16384]
    float* R    = ws + 4194304;            // 16,777,216 temp arena
    float* COMB = ws + 20971520;           // 1,310,720  [256][5120] tr|det state
    float* Z0   = ws + 22282240;           // 1,053,700
    float* U    = ws + 23335940;           //     1,028
    float* V    = ws + 23336968;           //     4,100
    // fuser / det-enc arena:
    float* Qf = R;
    float* Kf = R + 4194304;
    float* Vf = R + 8388608;               // fuser only
    float* MS = R + 12582912;              // fuser only
    // GNN arena (N=5120):
    float* QKV = R;                       // [768][5120]
    float* H   = R + 1310720;             // [512][5120] (overlays dead QKV tail)
    float* MSG = R + 3932160;             // [256][5120]
    float* M   = R + 5242880;             // [256][5120]; det-PE before GNN; final proj after
    // attn split-K partials (GNN loop only; overlays M which is dead there):
    _Float16* PO = (_Float16*)(R + 5242880);  // [320*4][64][64] halves = 5,242,880 h
    float* PM = R + 7864320;                  // [320*4][64]
    float* PL = R + 7946240;                  // [320*4][64]; ends 8,028,160 < 8,388,608
    // fused msg-proj weights:
    //   fuser: fp16 planes in COMB region (dead until meanpool)
    _Float16* Whff = (_Float16*)COMB;             // [4][512][256] halves
    _Float16* Wlff = (_Float16*)(COMB + 262144);  // [4][512][256] halves
    float* bcf = COMB + 524288;                   // [4][512]
    //   GNN plane arena: old Vf/MS region (free after fuser; 8.39M floats)
    _Float16* GP   = (_Float16*)(R + 8388608);
    _Float16* gph  = GP;                 // gnn_pw planes: [12][768][256]
    _Float16* gpl  = GP + 2359296;
    _Float16* gm1h = GP + 4718592;       // gnn_m1w x-part: [12][512][256]
    _Float16* gm1l = GP + 6291456;
    _Float16* gm2h = GP + 7864320;       // gnn_m2w: [12][256][512]
    _Float16* gm2l = GP + 9437184;
    _Float16* wfh  = GP + 11010048;      // GNN Wf = m1wB@mw: [12][512][256]
    _Float16* wfl  = GP + 12582912;
    _Float16* fnh  = GP + 14155776;      // final_w: [256][256]
    _Float16* fnl  = GP + 14221312;      // ends 14,286,848 halves
    float* bcg = R + 15600000;           // [12][512]
    float* Z0T = R;                      // sinkhorn transpose (end phase)
    // fp16 hi/lo weight-plane arena (fuser path), in HALVES from base:
    _Float16* PB = (_Float16*)(ws + 23400000);
    _Float16* e1h = PB;              _Float16* e1l = PB + 65536;
    _Float16* e2h = PB + 131072;     _Float16* e2l = PB + 196608;
    _Float16* pwh = PB + 262144;     _Float16* pwl = PB + 1048576;   // 4x196608
    _Float16* m1h = PB + 1835008;    _Float16* m1l = PB + 2883584;   // 4x262144 (full 512-wide)
    _Float16* m2h = PB + 3932160;    _Float16* m2l = PB + 4456448;   // 4x131072

    // ===== weight-plane precompute (independent; before everything) =======
    split_multi_kernel<<<9728, 256, 0, stream>>>(
        enc_w1, e1h, e1l, 256, 0,
        enc_w2, e2h, e2l, 512, 0,
        fus_pw, pwh, pwl, 3584, 0,
        fus_m1w, m1h, m1l, 7680, 0,
        fus_m2w, m2h, m2l, 9728, 0);
    fusewh_kernel<<<dim3(2, 8, 4), 256, 0, stream>>>(fus_m1w, fus_mw, Whff, Wlff);
    fusebias_kernel<<<dim3(2, 4), 256, 0, stream>>>(fus_m1w, fus_mb, fus_m1b, bcf);

    // ================= encoder (tracks) + fuser ===========================
    pe_kernel<<<dim3(NCT/256, 4), 256, 0, stream>>>(trk_in, MS, NCT, 4, 257*16);
    repack_kernel<<<dim3(NCT/256, 256), 256, 0, stream>>>(trk_in, Qf, NCT, 4, 257*16);
    gemmP64(stream, e1h, e1l, 256, e1h, e1l, 256, Qf, Qf, 256,
            enc_b1, nullptr, 0, Kf, NCT, 256, 256, NCT, 1);
    gemmP64(stream, e2h, e2l, 256, e2h, e2l, 256, Kf, Kf, 256,
            enc_b2, MS, NCT, XF, NCT, 256, 256, NCT, 0);

    for (int l = 0; l < 4; ++l) {
        gemmP64(stream, pwh + l*196608, pwl + l*196608, 256,
                pwh, pwl, 256, XF, XF, 256,
                fus_pb + l*768, nullptr, 0, Qf, NCT, 768, 256, NCT, 0);
        fuser_attn_kernel<<<1024, 256, 0, stream>>>(Qf, Kf, Vf, MS);
        gemmP64(stream, m1h + l*262144, m1l + l*262144, 512,
                Whff + l*131072, Wlff + l*131072, 256, XF, MS, 256,
                bcf + l*512, nullptr, 0, Kf, NCT, 512, 512, NCT, 1);
        gemmP64(stream, m2h + l*131072, m2l + l*131072, 512,
                m2h, m2l, 512, Kf, Kf, 512,
                fus_m2b + l*256, XF, NCT, XF, NCT, 256, 512, NCT, 0);
    }

    // ===== GNN plane precompute (old Vf/MS region now free) ===============
    split_multi_kernel<<<21760, 256, 0, stream>>>(
        gnn_pw, gph, gpl, 9216, 0,
        gnn_m1w, gm1h, gm1l, 15360, 512,
        gnn_m2w, gm2h, gm2l, 21504, 0,
        final_w, fnh, fnl, 21760, 0,
        final_w, fnh, fnl, 21760, 0);
    fusewh_kernel<<<dim3(2, 8, 12), 256, 0, stream>>>(gnn_m1w, gnn_mw, wfh, wfl);
    fusebias_kernel<<<dim3(2, 12), 256, 0, stream>>>(gnn_m1w, gnn_mb, gnn_m1b, bcg);

    meanpool_kernel<<<dim3(4, 256), 256, 0, stream>>>(XF, COMB);   // tr cols [0,1024)

    // ================= encoder (detections) -> COMB cols [1024,5120) ======
    pe_kernel<<<dim3(NCD/256, 4), 256, 0, stream>>>(det_in, M, NCD, 10, 257*1024);
    repack_kernel<<<dim3(NCD/256, 256), 256, 0, stream>>>(det_in, Qf, NCD, 10, 257*1024);
    gemmP64(stream, e1h, e1l, 256, e1h, e1l, 256, Qf, Qf, 256,
            enc_b1, nullptr, 0, Kf, NCD, 256, 256, NCD, 1);
    gemmP64(stream, e2h, e2l, 256, e2h, e2l, 256, Kf, Kf, 256,
            enc_b2, M, NCD, COMB + 1024, NCB, 256, 256, NCD, 0);

    // ================= GNN (combined tr|det, N=5120) ======================
    for (int l = 0; l < 12; ++l) {
        const _Float16* lph = gph + l*196608;
        const _Float16* lpl = gpl + l*196608;
        const float* pb  = gnn_pb + l*768;
        const float* m2b = gnn_m2b + l*256;
        const int cross = (l & 1);

        gemmP64(stream, lph, lpl, 256, lph, lpl, 256, COMB, COMB, 256,
                pb, nullptr, 0, QKV, NCB, 768, 256, NCB, 0);
        attn2_kernel<<<dim3(80, 4, 4), 256, 0, stream>>>(QKV, PO, PM, PL, cross);
        attn_merge_kernel<<<dim3(20, 4, 4), 256, 0, stream>>>(PO, PM, PL, MSG);
        gemmP64(stream, gm1h + l*131072, gm1l + l*131072, 256,
                wfh + l*131072, wfl + l*131072, 256, COMB, MSG, 256,
                bcg + l*512, nullptr, 0, H, NCB, 512, 512, NCB, 1);
        gemmP64(stream, gm2h + l*131072, gm2l + l*131072, 512,
                gm2h + l*131072, gm2l + l*131072, 512, H, H, 512,
                m2b, COMB, NCB, COMB, NCB, 256, 512, NCB, 0);
    }

    // ================= final projection + scores + sinkhorn ===============
    gemmP64(stream, fnh, fnl, 256, fnh, fnl, 256, COMB, COMB, 256,
            final_b, nullptr, 0, M, NCB, 256, 256, NCB, 0);
    scores_kernel<<<dim3(16, 4, 4), 256, 0, stream>>>(M, Z0, Z0T);
    sink_init_kernel<<<21, 256, 0, stream>>>(Z0, Z0T, V, bin_sc);
    for (int it = 0; it < SINK_IT; ++it) {
        sink_u_kernel<<<257, 256, 0, stream>>>(Z0, V, U);
        sink_v_kernel<<<1025, 256, 0, stream>>>(Z0T, U, V);
    }
    sink_out_kernel<<<dim3(5, 257, 4), 256, 0, stream>>>(Z0, U, V, out);
}

// Round 13
// 2507.040 us; speedup vs baseline: 1.0392x; 1.0392x over previous
//
#include <hip/hip_runtime.h>
#include <math.h>

// ---------------------------------------------------------------------------
// Associator forward. GEMMs (R12): PURE FP16 inputs — A-hi plane x B-hi,
// fp32 accumulate. R11 counters: duration unchanged at 2x occupancy ->
// k-step chain VALU-bound (B split-convert 48 ops/thread/step, VALUBusy 35%
// vs MfmaUtil 10%). Dropping B-lo halves converts+MFMA+frag-reads; LDS
// 24->14.5KB. Per-GEMM rel err ~1e-3 (fp16 rounding, fp32 acc).
// Layouts: activations are [C][Ncols] row-major fp32.
//   trk cols: 16384 (track*16+t); GNN combined cols: 5120 = [tr: b*256+n | 1024 + det: b*1024+m]
// A planes staged via global_load_lds (16B DMA) into LINEAR LDS; fragment
// reads XOR-swizzled.
// attn2: flash SPLIT-K (S=4) + lo-plane drop (Q split, K/P/V hi-only).
// Sinkhorn: fp32, 60 iters x 2 micro-launches (launch-bound; persistent
// barrier 20us/barrier = 2x worse R5; fp16 Z0 = null R7).
// ---------------------------------------------------------------------------

#define NCT 16384
#define NCD 4096
#define NCB 5120
#define ZROW 257
#define ZCOL 1025
#define ZBAT (ZROW*ZCOL)   // 263425

#define SINK_IT 60

#define NORM_C  (-7.1546153569f)   // -log(1280)
#define LOG_NS  (6.9314718056f)    // log(1024)
#define LOG_MS  (5.5451774445f)    // log(256)
#define LOG_TOT (7.1546153569f)    // +log(1280)

typedef _Float16 f16x8 __attribute__((ext_vector_type(8)));
typedef _Float16 f16x4 __attribute__((ext_vector_type(4)));
typedef float f32x4 __attribute__((ext_vector_type(4)));

#define APAD 40   // LDS row stride in halves for B tiles (80 B; 2-way banks)

// 16B global->LDS stage. DMA path: per-lane global addr g, wave-uniform LDS
// base; HW places lane i at base + 16i. Fallback reproduces the placement.
__device__ __forceinline__ void stage16(const _Float16* g, _Float16* ldsbase, int lane)
{
#if __has_builtin(__builtin_amdgcn_global_load_lds)
    __builtin_amdgcn_global_load_lds(
        (const __attribute__((address_space(1))) unsigned int*)(const void*)g,
        (__attribute__((address_space(3))) unsigned int*)(void*)ldsbase, 16, 0, 0);
#else
    *(f16x8*)(ldsbase + lane * 8) = *(const f16x8*)g;
#endif
}

// ---------------- GEMM 64x128 tile (ALL gemms; A-hi x B-hi) ----------------
// out = [W0|W1] @ [X0;X1] + bias (+res) (relu?). A-side from fp16 hi plane:
// k<C0 from Ph0 (stride S0 halves), k>=C0 from Ph1 (stride S1).
// C0%32==0 so a 32-wide k-tile never straddles.
__global__ __launch_bounds__(256) void gemm64p_kernel(
    const _Float16* __restrict__ Ph0, const _Float16* __restrict__ Pl0, int S0,
    const _Float16* __restrict__ Ph1, const _Float16* __restrict__ Pl1, int S1,
    const float* __restrict__ X0, const float* __restrict__ X1,
    const float* __restrict__ bias, const float* __restrict__ res,
    float* __restrict__ out,
    int O, int C, int C0, int N, int Nr, int No, int relu)
{
    __shared__ _Float16 Ah[64][32];
    __shared__ _Float16 Bh[128][APAD];
    const int tid = threadIdx.x;
    const int n0 = blockIdx.x * 128, m0 = blockIdx.y * 64;
    const int wave = tid >> 6, lane = tid & 63;
    const int wo = (wave >> 1) * 32, wn = (wave & 1) * 64;
    const int lm = lane & 15, lq = lane >> 4;
    // A DMA: lane i -> LDS row r0+(i>>2), 16B slot (i&3). Swizzle: slot s of
    // row R holds k-chunk s ^ ((R>>1)&3)  =>  lane fetches chunk
    // (i&3)^((i>>3)&3); read of k-chunk lq at row R uses slot lq^((R>>1)&3).
    const int sar = lane >> 2;
    const int sakx = ((lane & 3) ^ ((lane >> 3) & 3)) * 8;
    const int asw = (lq ^ ((lm >> 1) & 3)) * 8;   // swizzled A-frag k-offset
    const int bkg = tid & 7, bng = tid >> 3;

    f32x4 acc[2][4] = {};

    for (int kb = 0; kb < C; kb += 32) {
        float4 xv[4];
        #pragma unroll
        for (int r = 0; r < 4; ++r) {
            const int krow = kb + bkg * 4 + r;
            const float* xs = (krow < C0) ? X0 + (size_t)krow * N
                                          : X1 + (size_t)(krow - C0) * N;
            xv[r] = *(const float4*)(xs + n0 + bng * 4);
        }
        const bool s0 = (kb < C0);
        const _Float16* ph = s0 ? Ph0 : Ph1;
        const int S = s0 ? S0 : S1;
        const int kc = s0 ? kb : kb - C0;
        __syncthreads();
        // ---- A: 16B DMA of hi plane (one instr per wave) ----
        {
            const int r0 = wave * 16;
            const size_t go = (size_t)(m0 + r0 + sar) * S + kc + sakx;
            stage16(ph + go, &Ah[r0][0], lane);
        }
        // ---- B: hi convert + transposed store ----
        #pragma unroll
        for (int j = 0; j < 4; ++j) {
            _Float16 hb[4];
            #pragma unroll
            for (int r = 0; r < 4; ++r)
                hb[r] = (_Float16)((const float*)&xv[r])[j];
            *(f16x4*)&Bh[bng * 4 + j][bkg * 4] = *(const f16x4*)&hb[0];
        }
        __syncthreads();
        f16x8 bh[4];
        #pragma unroll
        for (int t = 0; t < 4; ++t)
            bh[t] = *(const f16x8*)&Bh[wn + t * 16 + lm][lq * 8];
        #pragma unroll
        for (int mt = 0; mt < 2; ++mt) {
            const f16x8 ah = *(const f16x8*)&Ah[wo + mt * 16 + lm][asw];
            #pragma unroll
            for (int nt = 0; nt < 4; ++nt)
                acc[mt][nt] = __builtin_amdgcn_mfma_f32_16x16x32_f16(ah, bh[nt], acc[mt][nt], 0, 0, 0);
        }
    }
    #pragma unroll
    for (int mt = 0; mt < 2; ++mt) {
        #pragma unroll
        for (int rg = 0; rg < 4; ++rg) {
            const int o = m0 + wo + mt * 16 + lq * 4 + rg;
            const float bs = bias[o];
            #pragma unroll
            for (int nt = 0; nt < 4; ++nt) {
                const int n = n0 + wn + nt * 16 + lm;
                float v = acc[mt][nt][rg] + bs;
                if (res) v += res[(size_t)o * Nr + n];
                if (relu) v = fmaxf(v, 0.f);
                out[(size_t)o * No + n] = v;
            }
        }
    }
}

// ---------------- merged weight split: fp32 -> fp16 hi/lo planes -----------
__global__ void split_multi_kernel(
    const float* __restrict__ s0, _Float16* __restrict__ h0, _Float16* __restrict__ l0, int c0, int st0,
    const float* __restrict__ s1, _Float16* __restrict__ h1, _Float16* __restrict__ l1, int c1, int st1,
    const float* __restrict__ s2, _Float16* __restrict__ h2, _Float16* __restrict__ l2, int c2, int st2,
    const float* __restrict__ s3, _Float16* __restrict__ h3, _Float16* __restrict__ l3, int c3, int st3,
    const float* __restrict__ s4, _Float16* __restrict__ h4, _Float16* __restrict__ l4, int c4, int st4)
{
    int b = blockIdx.x;
    const float* s; _Float16* h; _Float16* l; int st;
    if      (b < c0) {               s = s0; h = h0; l = l0; st = st0; }
    else if (b < c1) { b -= c0;      s = s1; h = h1; l = l1; st = st1; }
    else if (b < c2) { b -= c1;      s = s2; h = h2; l = l2; st = st2; }
    else if (b < c3) { b -= c2;      s = s3; h = h3; l = l3; st = st3; }
    else             { b -= c3;      s = s4; h = h4; l = l4; st = st4; }
    const int i = b * 256 + threadIdx.x;
    const float x = st ? s[(size_t)(i >> 8) * st + (i & 255)] : s[i];
    const _Float16 hh = (_Float16)x;
    h[i] = hh;
    l[i] = (_Float16)(x - (float)hh);
}

// ---------------- batched Wf = m1wB @ mw, fp16-plane out -------------------
__global__ __launch_bounds__(256) void fusewh_kernel(
    const float* __restrict__ m1w_base, const float* __restrict__ mw_base,
    _Float16* __restrict__ wfh_base, _Float16* __restrict__ wfl_base)
{
    const int z = blockIdx.z;
    const float* A = m1w_base + (size_t)z * 262144 + 256;
    const float* B = mw_base + (size_t)z * 65536;
    _Float16* oh = wfh_base + (size_t)z * 131072;
    _Float16* ol = wfl_base + (size_t)z * 131072;
    __shared__ _Float16 Ah[64][APAD], Al[64][APAD];
    __shared__ _Float16 Bh[128][APAD], Bl[128][APAD];
    const int tid = threadIdx.x;
    const int n0 = blockIdx.x * 128, m0 = blockIdx.y * 64;
    const int wave = tid >> 6, lane = tid & 63;
    const int wo = (wave >> 1) * 32, wn = (wave & 1) * 64;
    const int lm = lane & 15, lq = lane >> 4;
    const int ar = tid >> 2, ak8 = (tid & 3) << 3;
    const int bkg = tid & 7, bng = tid >> 3;

    f32x4 acc[2][4] = {};
    for (int kb = 0; kb < 256; kb += 32) {
        float4 av[2];
        const float* wp = A + (size_t)(m0 + ar) * 512 + kb + ak8;
        av[0] = *(const float4*)(wp);
        av[1] = *(const float4*)(wp + 4);
        float4 xv[4];
        #pragma unroll
        for (int r = 0; r < 4; ++r)
            xv[r] = *(const float4*)(B + (size_t)(kb + bkg * 4 + r) * 256 + n0 + bng * 4);
        __syncthreads();
        {
            _Float16 hbuf[8], lbuf[8];
            #pragma unroll
            for (int q = 0; q < 2; ++q) {
                const float* f = (const float*)&av[q];
                #pragma unroll
                for (int c = 0; c < 4; ++c) {
                    const float x = f[c];
                    const _Float16 h = (_Float16)x;
                    hbuf[q * 4 + c] = h;
                    lbuf[q * 4 + c] = (_Float16)(x - (float)h);
                }
            }
            *(f16x8*)&Ah[ar][ak8] = *(const f16x8*)&hbuf[0];
            *(f16x8*)&Al[ar][ak8] = *(const f16x8*)&lbuf[0];
        }
        #pragma unroll
        for (int j = 0; j < 4; ++j) {
            _Float16 hb[4], lb[4];
            #pragma unroll
            for (int r = 0; r < 4; ++r) {
                const float x = ((const float*)&xv[r])[j];
                const _Float16 h = (_Float16)x;
                hb[r] = h;
                lb[r] = (_Float16)(x - (float)h);
            }
            *(f16x4*)&Bh[bng * 4 + j][bkg * 4] = *(const f16x4*)&hb[0];
            *(f16x4*)&Bl[bng * 4 + j][bkg * 4] = *(const f16x4*)&lb[0];
        }
        __syncthreads();
        f16x8 bh[4], bl[4];
        #pragma unroll
        for (int t = 0; t < 4; ++t) {
            bh[t] = *(const f16x8*)&Bh[wn + t * 16 + lm][lq * 8];
            bl[t] = *(const f16x8*)&Bl[wn + t * 16 + lm][lq * 8];
        }
        #pragma unroll
        for (int mt = 0; mt < 2; ++mt) {
            const f16x8 ah = *(const f16x8*)&Ah[wo + mt * 16 + lm][lq * 8];
            const f16x8 al = *(const f16x8*)&Al[wo + mt * 16 + lm][lq * 8];
            #pragma unroll
            for (int nt = 0; nt < 4; ++nt) {
                acc[mt][nt] = __builtin_amdgcn_mfma_f32_16x16x32_f16(ah, bh[nt], acc[mt][nt], 0, 0, 0);
                acc[mt][nt] = __builtin_amdgcn_mfma_f32_16x16x32_f16(ah, bl[nt], acc[mt][nt], 0, 0, 0);
                acc[mt][nt] = __builtin_amdgcn_mfma_f32_16x16x32_f16(al, bh[nt], acc[mt][nt], 0, 0, 0);
            }
        }
    }
    #pragma unroll
    for (int mt = 0; mt < 2; ++mt)
        #pragma unroll
        for (int rg = 0; rg < 4; ++rg) {
            const int o = m0 + wo + mt * 16 + lq * 4 + rg;
            #pragma unroll
            for (int nt = 0; nt < 4; ++nt) {
                const float v = acc[mt][nt][rg];
                const _Float16 hh = (_Float16)v;
                oh[(size_t)o * 256 + n0 + wn + nt * 16 + lm] = hh;
                ol[(size_t)o * 256 + n0 + wn + nt * 16 + lm] = (_Float16)(v - (float)hh);
            }
        }
}

// ---------------- batched bc = m1wB @ mb + m1b -----------------------------
__global__ void fusebias_kernel(const float* __restrict__ m1w_base,
                                const float* __restrict__ mb_base,
                                const float* __restrict__ m1b_base,
                                float* __restrict__ bc_base)
{
    const int z = blockIdx.y;
    const int o = blockIdx.x * 256 + threadIdx.x;   // 0..511
    const float* A = m1w_base + (size_t)z * 262144 + (size_t)o * 512 + 256;
    const float* mb = mb_base + z * 256;
    float s = m1b_base[z * 512 + o];
    for (int c = 0; c < 256; ++c) s = fmaf(A[c], mb[c], s);
    bc_base[z * 512 + o] = s;
}

// ---------------- positional encoding (grid.y splits the 128 i's) ---------
__global__ void pe_kernel(const float* __restrict__ src, float* __restrict__ pe,
                          int N, int shift, int cstride)
{
    const int col = blockIdx.x * 256 + threadIdx.x;
    if (col >= N) return;
    const int seg = 1 << shift;
    const int i0 = blockIdx.y * 32;
    const float pos = src[(size_t)(col >> shift) * cstride + (col & (seg - 1))];
    #pragma unroll 4
    for (int i = i0; i < i0 + 32; ++i) {
        const float div = expf((float)i * -0.07195578415606394f); // -ln(10000)/128
        const float ang = pos * div;
        pe[(size_t)(2*i) * N + col]   = sinf(ang);
        pe[(size_t)(2*i+1) * N + col] = cosf(ang);
    }
}

// ---------------- input repack (drop channel 0) ---------------------------
__global__ void repack_kernel(const float* __restrict__ src, float* __restrict__ dst,
                              int N, int shift, int cstride)
{
    const int col = blockIdx.x * 256 + threadIdx.x;
    const int c = blockIdx.y;
    if (col >= N) return;
    const int seg = 1 << shift;
    dst[(size_t)c * N + col] =
        src[(size_t)(col >> shift) * cstride + (size_t)(c + 1) * seg + (col & (seg - 1))];
}

// ---------------- fuser self-attention over time (n=m=16 per track) -------
__global__ __launch_bounds__(256) void fuser_attn_kernel(
    const float* __restrict__ Qb, const float* __restrict__ Kb,
    const float* __restrict__ Vb, float* __restrict__ Ob)
{
    __shared__ float qs[256][17], ks[256][17], vs[256][17];
    __shared__ float ps[4][16][17];
    const int trk = blockIdx.x, tid = threadIdx.x;
    const int col0 = trk * 16;
    for (int idx = tid; idx < 1024; idx += 256) {
        const int r = idx >> 2, seg = (idx & 3) << 2;
        const float4 q = *(const float4*)&Qb[(size_t)r * NCT + col0 + seg];
        const float4 k = *(const float4*)&Kb[(size_t)r * NCT + col0 + seg];
        const float4 v = *(const float4*)&Vb[(size_t)r * NCT + col0 + seg];
        qs[r][seg]=q.x; qs[r][seg+1]=q.y; qs[r][seg+2]=q.z; qs[r][seg+3]=q.w;
        ks[r][seg]=k.x; ks[r][seg+1]=k.y; ks[r][seg+2]=k.z; ks[r][seg+3]=k.w;
        vs[r][seg]=v.x; vs[r][seg+1]=v.y; vs[r][seg+2]=v.z; vs[r][seg+3]=v.w;
    }
    __syncthreads();
    {
        const int g = tid >> 2, h = g >> 4, n = g & 15, mb = (tid & 3) << 2;
        float s[4] = {};
        #pragma unroll 4
        for (int hd = 0; hd < 64; ++hd) {
            const int c = hd*4 + h;
            const float q = qs[c][n];
            #pragma unroll
            for (int j = 0; j < 4; ++j) s[j] = fmaf(q, ks[c][mb + j], s[j]);
        }
        #pragma unroll
        for (int j = 0; j < 4; ++j) ps[h][n][mb + j] = s[j] * 0.125f;
    }
    __syncthreads();
    if (tid < 64) {
        const int hh = tid >> 4, nn = tid & 15;
        float mx = -INFINITY;
        for (int m = 0; m < 16; ++m) mx = fmaxf(mx, ps[hh][nn][m]);
        float sum = 0.f;
        for (int m = 0; m < 16; ++m) { const float p = expf(ps[hh][nn][m] - mx);
                                       ps[hh][nn][m] = p; sum += p; }
        const float inv = 1.f / sum;
        for (int m = 0; m < 16; ++m) ps[hh][nn][m] *= inv;
    }
    __syncthreads();
    {
        const int c = tid, hc = c & 3;
        float msg[16];
        #pragma unroll
        for (int n = 0; n < 16; ++n) {
            float a = 0.f;
            #pragma unroll
            for (int m = 0; m < 16; ++m) a = fmaf(ps[hc][n][m], vs[c][m], a);
            msg[n] = a;
        }
        __syncthreads();
        #pragma unroll
        for (int n = 0; n < 16; ++n) qs[c][n] = msg[n];
    }
    __syncthreads();
    for (int idx = tid; idx < 1024; idx += 256) {
        const int r = idx >> 2, seg = (idx & 3) << 2;
        *(float4*)&Ob[(size_t)r * NCT + col0 + seg] =
            make_float4(qs[r][seg], qs[r][seg+1], qs[r][seg+2], qs[r][seg+3]);
    }
}

// ---------------- GNN attention: fp16 MFMA flash, SPLIT-K (S=4) -----------
// grid.x = 80: nt_raw = x>>2 (LPT remap), s = x&3 -> m-tiles [s*cnt, s*cnt+cnt).
// Q split (hi+lo), K/P/V hi-only: QK 2 MFMA, PV 1 MFMA per frag pair.
// Writes unnormalized partials: PO fp16 [qt][s][64 q][64 d], PM/PL fp32.
// LDS: 2 buffers (K/P | V), Q staged through them before the loop.
__global__ __launch_bounds__(256) void attn2_kernel(
    const float* __restrict__ QKV, _Float16* __restrict__ PO,
    float* __restrict__ PM, float* __restrict__ PL, int cross)
{
    __shared__ _Float16 SH[2][64][72];
    _Float16 (*Kh)[72] = SH[0];   // K hi; P hi after QK; Q hi at start
    _Float16 (*Vh)[72] = SH[1];   // V hi; Q lo at start
    const int b = blockIdx.z, h = blockIdx.y;
    const int raw = blockIdx.x;
    const int sp = raw & 3;
    const int nt_raw = raw >> 2;
    const int nt = cross ? nt_raw : ((nt_raw < 16) ? (nt_raw + 4) : (nt_raw - 16));
    const float* Qb = QKV;
    const float* Kb = QKV + (size_t)256 * NCB;
    const float* Vb = QKV + (size_t)512 * NCB;
    int qcol, kbase, nk;
    if (nt < 4) {
        qcol = b * 256 + nt * 64;
        if (cross) { kbase = 1024 + b * 1024; nk = 1024; }
        else       { kbase = b * 256;         nk = 256;  }
    } else {
        qcol = 1024 + b * 1024 + (nt - 4) * 64;
        if (cross) { kbase = b * 256;         nk = 256;  }
        else       { kbase = 1024 + b * 1024; nk = 1024; }
    }
    const int tid = threadIdx.x;
    const int wave = tid >> 6, lane = tid & 63;
    const int lm = lane & 15, quad = lane >> 4;
    const int dg = tid & 15, qg = tid >> 4;
    const int vd = tid >> 2, vseg = (tid & 3) * 16;
    const int vchan = vd * 4 + h;

    // ---- Q stage (hi->Kh, lo->Vh) + consume to regs ----
    {
        float4 xv[4];
        #pragma unroll
        for (int r = 0; r < 4; ++r) {
            const int chan = (dg * 4 + r) * 4 + h;
            xv[r] = *(const float4*)&Qb[(size_t)chan * NCB + qcol + qg * 4];
        }
        #pragma unroll
        for (int j = 0; j < 4; ++j) {
            _Float16 hb[4], lb[4];
            #pragma unroll
            for (int r = 0; r < 4; ++r) {
                const float x = ((const float*)&xv[r])[j];
                const _Float16 hh = (_Float16)x;
                hb[r] = hh; lb[r] = (_Float16)(x - (float)hh);
            }
            *(f16x4*)&Kh[qg * 4 + j][dg * 4] = *(const f16x4*)hb;
            *(f16x4*)&Vh[qg * 4 + j][dg * 4] = *(const f16x4*)lb;
        }
    }
    __syncthreads();
    f16x8 qh[2], ql[2];
    #pragma unroll
    for (int ks = 0; ks < 2; ++ks) {
        qh[ks] = *(const f16x8*)&Kh[wave * 16 + lm][ks * 32 + quad * 8];
        ql[ks] = *(const f16x8*)&Vh[wave * 16 + lm][ks * 32 + quad * 8];
    }

    float rmax[4], rsum[4];
    #pragma unroll
    for (int r = 0; r < 4; ++r) { rmax[r] = -INFINITY; rsum[r] = 0.f; }
    f32x4 acco[4] = {};

    const int mtn = nk >> 6;
    const int cnt = mtn >> 2;       // S=4 parts
    const int mt0 = sp * cnt;
    const int mtE = mt0 + cnt;
    float4 kxv[4], vxv[4];
    {
        const int kcol = kbase + mt0 * 64;
        #pragma unroll
        for (int r = 0; r < 4; ++r) {
            const int chan = (dg * 4 + r) * 4 + h;
            kxv[r] = *(const float4*)&Kb[(size_t)chan * NCB + kcol + qg * 4];
        }
        #pragma unroll
        for (int q = 0; q < 4; ++q)
            vxv[q] = *(const float4*)&Vb[(size_t)vchan * NCB + kcol + vseg + q * 4];
    }
    for (int mt = mt0; mt < mtE; ++mt) {
        __syncthreads();   // prior tile's (or Q's) fragment reads complete
        // ---- K hi convert+store ----
        #pragma unroll
        for (int j = 0; j < 4; ++j) {
            _Float16 hb[4];
            #pragma unroll
            for (int r = 0; r < 4; ++r)
                hb[r] = (_Float16)((const float*)&kxv[r])[j];
            *(f16x4*)&Kh[qg * 4 + j][dg * 4] = *(const f16x4*)hb;
        }
        // ---- V hi convert+store ----
        {
            _Float16 vh16[16];
            #pragma unroll
            for (int q = 0; q < 4; ++q) {
                const float* f = (const float*)&vxv[q];
                #pragma unroll
                for (int c = 0; c < 4; ++c) vh16[q*4+c] = (_Float16)f[c];
            }
            *(f16x8*)&Vh[vd][vseg]     = *(const f16x8*)&vh16[0];
            *(f16x8*)&Vh[vd][vseg + 8] = *(const f16x8*)&vh16[8];
        }
        __syncthreads();
        // ---- issue next tile's loads (overlap QK+softmax+PV below) ----
        if (mt + 1 < mtE) {
            const int kcol = kbase + (mt + 1) * 64;
            #pragma unroll
            for (int r = 0; r < 4; ++r) {
                const int chan = (dg * 4 + r) * 4 + h;
                kxv[r] = *(const float4*)&Kb[(size_t)chan * NCB + kcol + qg * 4];
            }
            #pragma unroll
            for (int q = 0; q < 4; ++q)
                vxv[q] = *(const float4*)&Vb[(size_t)vchan * NCB + kcol + vseg + q * 4];
        }
        // ---- QK: full Q x K-hi (2 MFMA per frag pair) ----
        f32x4 accs[4] = {};
        #pragma unroll
        for (int t = 0; t < 4; ++t) {
            #pragma unroll
            for (int ks = 0; ks < 2; ++ks) {
                const f16x8 kh = *(const f16x8*)&Kh[t * 16 + lm][ks * 32 + quad * 8];
                accs[t] = __builtin_amdgcn_mfma_f32_16x16x32_f16(qh[ks], kh, accs[t], 0,0,0);
                accs[t] = __builtin_amdgcn_mfma_f32_16x16x32_f16(ql[ks], kh, accs[t], 0,0,0);
            }
        }
        float alpha[4];
        float psv[4][4];
        #pragma unroll
        for (int r = 0; r < 4; ++r) {
            float mx = fmaxf(fmaxf(accs[0][r], accs[1][r]),
                             fmaxf(accs[2][r], accs[3][r])) * 0.125f;
            #pragma unroll
            for (int off = 1; off < 16; off <<= 1) mx = fmaxf(mx, __shfl_xor(mx, off));
            const float mnew = fmaxf(rmax[r], mx);
            alpha[r] = expf(rmax[r] - mnew);
            rmax[r] = mnew;
            float s = 0.f;
            #pragma unroll
            for (int t = 0; t < 4; ++t) {
                const float p = expf(accs[t][r] * 0.125f - mnew);
                psv[t][r] = p; s += p;
            }
            #pragma unroll
            for (int off = 1; off < 16; off <<= 1) s += __shfl_xor(s, off);
            rsum[r] = rsum[r] * alpha[r] + s;
        }
        __syncthreads();
        // ---- P hi store (into Kh) ----
        #pragma unroll
        for (int t = 0; t < 4; ++t)
            #pragma unroll
            for (int r = 0; r < 4; ++r)
                Kh[wave * 16 + quad * 4 + r][t * 16 + lm] = (_Float16)psv[t][r];
        __syncthreads();
        #pragma unroll
        for (int td = 0; td < 4; ++td)
            #pragma unroll
            for (int r = 0; r < 4; ++r) acco[td][r] *= alpha[r];
        // ---- PV: P-hi x V-hi (1 MFMA per frag pair) ----
        #pragma unroll
        for (int ks = 0; ks < 2; ++ks) {
            const f16x8 ph = *(const f16x8*)&Kh[wave * 16 + lm][ks * 32 + quad * 8];
            #pragma unroll
            for (int td = 0; td < 4; ++td) {
                const f16x8 vh = *(const f16x8*)&Vh[td * 16 + lm][ks * 32 + quad * 8];
                acco[td] = __builtin_amdgcn_mfma_f32_16x16x32_f16(ph, vh, acco[td], 0,0,0);
            }
        }
    }
    // ---- write partials (unnormalized acc + m/l per q-row) ----
    const int qt = ((b * 4 + h) * 20 + nt);
    _Float16* po = PO + ((size_t)(qt * 4 + sp) * 64) * 64;
    #pragma unroll
    for (int td = 0; td < 4; ++td)
        #pragma unroll
        for (int r = 0; r < 4; ++r)
            po[(wave * 16 + quad * 4 + r) * 64 + td * 16 + lm] = (_Float16)acco[td][r];
    if (lm == 0) {
        #pragma unroll
        for (int r = 0; r < 4; ++r) {
            const int qrow = wave * 16 + quad * 4 + r;
            PM[(qt * 4 + sp) * 64 + qrow] = rmax[r];
            PL[(qt * 4 + sp) * 64 + qrow] = rsum[r];
        }
    }
}

// ---------------- flash merge of S=4 attn partials -> MSG -----------------
__global__ __launch_bounds__(256) void attn_merge_kernel(
    const _Float16* __restrict__ PO, const float* __restrict__ PM,
    const float* __restrict__ PL, float* __restrict__ MSG)
{
    const int b = blockIdx.z, h = blockIdx.y, nt = blockIdx.x;   // logical nt
    const int qcol = (nt < 4) ? (b * 256 + nt * 64) : (1024 + b * 1024 + (nt - 4) * 64);
    const int qt = ((b * 4 + h) * 20 + nt);
    const int tid = threadIdx.x;
    const int qp = tid & 63, cg = tid >> 6;
    float w[4];
    float mg = -INFINITY;
    #pragma unroll
    for (int s = 0; s < 4; ++s) { w[s] = PM[(qt * 4 + s) * 64 + qp]; mg = fmaxf(mg, w[s]); }
    float l = 0.f;
    #pragma unroll
    for (int s = 0; s < 4; ++s) {
        w[s] = expf(w[s] - mg);
        l += w[s] * PL[(qt * 4 + s) * 64 + qp];
    }
    const float invl = 1.f / l;
    f16x8 a0[4], a1[4];
    #pragma unroll
    for (int s = 0; s < 4; ++s) {
        const _Float16* base = PO + (((size_t)(qt * 4 + s) * 64 + qp) * 64 + cg * 16);
        a0[s] = *(const f16x8*)base;
        a1[s] = *(const f16x8*)(base + 8);
    }
    #pragma unroll
    for (int i = 0; i < 8; ++i) {
        float o = 0.f;
        #pragma unroll
        for (int s = 0; s < 4; ++s) o += w[s] * (float)a0[s][i];
        const int d = cg * 16 + i;
        MSG[(size_t)(d * 4 + h) * NCB + qcol + qp] = o * invl;
    }
    #pragma unroll
    for (int i = 0; i < 8; ++i) {
        float o = 0.f;
        #pragma unroll
        for (int s = 0; s < 4; ++s) o += w[s] * (float)a1[s][i];
        const int d = cg * 16 + 8 + i;
        MSG[(size_t)(d * 4 + h) * NCB + qcol + qp] = o * invl;
    }
}

// ---------------- mean pool over time (into combined cols [0,1024)) -------
__global__ void meanpool_kernel(const float* __restrict__ x, float* __restrict__ tr)
{
    const int trk = blockIdx.x * 256 + threadIdx.x;
    const int d = blockIdx.y;
    const float* p = x + (size_t)d * NCT + (size_t)trk * 16;
    float s = 0.f;
    #pragma unroll
    for (int t = 0; t < 16; ++t) s += p[t];
    tr[(size_t)d * NCB + trk] = s * 0.0625f;
}

// ---------------- scores = m0^T m1 / 16 into Z0 and Z0T -------------------
__global__ __launch_bounds__(256) void scores_kernel(
    const float* __restrict__ M, float* __restrict__ Z0, float* __restrict__ Z0T)
{
    __shared__ float As[8][68];
    __shared__ float Bs[8][68];
    const int bm = blockIdx.x, bn = blockIdx.y, b = blockIdx.z;
    const int tid = threadIdx.x;
    const int n0 = bn * 64, mm0 = bm * 64;
    const int tx = tid & 15, ty = tid >> 4;
    float acc[4][4] = {};
    for (int kb = 0; kb < 256; kb += 8) {
        __syncthreads();
        for (int idx = tid; idx < 512; idx += 256) {
            const int r = idx >> 6, cc = idx & 63;
            As[r][cc] = M[(size_t)(kb + r) * NCB + b * 256 + n0 + cc];
            Bs[r][cc] = M[(size_t)(kb + r) * NCB + 1024 + b * 1024 + mm0 + cc];
        }
        __syncthreads();
        #pragma unroll
        for (int kk = 0; kk < 8; ++kk) {
            float a[4], bv[4];
            #pragma unroll
            for (int i = 0; i < 4; ++i) { a[i] = As[kk][ty*4 + i]; bv[i] = Bs[kk][tx*4 + i]; }
            #pragma unroll
            for (int i = 0; i < 4; ++i)
                #pragma unroll
                for (int j = 0; j < 4; ++j) acc[i][j] = fmaf(a[i], bv[j], acc[i][j]);
        }
    }
    #pragma unroll
    for (int i = 0; i < 4; ++i)
        #pragma unroll
        for (int j = 0; j < 4; ++j) {
            const float s = acc[i][j] * 0.0625f;
            const int rr = n0 + ty*4 + i, cc = mm0 + tx*4 + j;
            Z0 [(size_t)b * ZBAT + (size_t)rr * ZCOL + cc] = s;
            Z0T[(size_t)b * ZBAT + (size_t)cc * ZROW + rr] = s;
        }
}

// ---------------- sinkhorn ------------------------------------------------
__global__ void sink_init_kernel(float* __restrict__ Z0, float* __restrict__ Z0T,
                                 float* __restrict__ v, const float* __restrict__ binp)
{
    const float alpha = binp[0];
    const int idx = blockIdx.x * 256 + threadIdx.x;
    if (idx < 4 * ZCOL) v[idx] = 0.f;
    if (idx < 4 * 1281) {
        const int b = idx / 1281, e = idx % 1281;
        if (e < 1025) Z0[(size_t)b * ZBAT + 256 * ZCOL + e] = alpha;
        else          Z0[(size_t)b * ZBAT + (size_t)(e - 1025) * ZCOL + 1024] = alpha;
    }
    if (idx < 4 * 1282) {
        const int b = idx / 1282, e = idx % 1282;
        if (e < 257) Z0T[(size_t)b * ZBAT + 1024 * ZROW + e] = alpha;
        else         Z0T[(size_t)b * ZBAT + (size_t)(e - 257) * ZROW + 256] = alpha;
    }
}

__global__ __launch_bounds__(256) void sink_u_kernel(
    const float* __restrict__ Z0, const float* __restrict__ v, float* __restrict__ u)
{
    const int w = threadIdx.x >> 6, lane = threadIdx.x & 63;
    const int row = blockIdx.x * 4 + w;          // 0..1027
    const int b = row / 257, i = row % 257;
    const float* z  = Z0 + (size_t)b * ZBAT + (size_t)i * ZCOL;
    const float* vb = v + b * ZCOL;
    float zz[17];
    float mx = -INFINITY;
    #pragma unroll
    for (int k = 0; k < 16; ++k) {
        zz[k] = z[lane + k*64] + vb[lane + k*64];
        mx = fmaxf(mx, zz[k]);
    }
    zz[16] = (lane == 0) ? (z[1024] + vb[1024]) : -INFINITY;
    mx = fmaxf(mx, zz[16]);
    #pragma unroll
    for (int off = 32; off; off >>= 1) mx = fmaxf(mx, __shfl_xor(mx, off));
    float s = 0.f;
    #pragma unroll
    for (int k = 0; k < 17; ++k) s += expf(zz[k] - mx);
    #pragma unroll
    for (int off = 32; off; off >>= 1) s += __shfl_xor(s, off);
    if (lane == 0) {
        const float lmu = (i < 256) ? NORM_C : (LOG_NS + NORM_C);
        u[b * 257 + i] = lmu - (mx + logf(s));
    }
}

__global__ __launch_bounds__(256) void sink_v_kernel(
    const float* __restrict__ Z0T, const float* __restrict__ u, float* __restrict__ v)
{
    const int w = threadIdx.x >> 6, lane = threadIdx.x & 63;
    const int row = blockIdx.x * 4 + w;          // 0..4099
    const int b = row / 1025, j = row - b * 1025;
    const float* z  = Z0T + (size_t)b * ZBAT + (size_t)j * ZROW;
    const float* ub = u + b * 257;
    float zz[5];
    float mx = -INFINITY;
    #pragma unroll
    for (int k = 0; k < 4; ++k) {
        zz[k] = z[lane + k*64] + ub[lane + k*64];
        mx = fmaxf(mx, zz[k]);
    }
    zz[4] = (lane == 0) ? (z[256] + ub[256]) : -INFINITY;
    mx = fmaxf(mx, zz[4]);
    #pragma unroll
    for (int off = 32; off; off >>= 1) mx = fmaxf(mx, __shfl_xor(mx, off));
    float s = 0.f;
    #pragma unroll
    for (int k = 0; k < 5; ++k) s += expf(zz[k] - mx);
    #pragma unroll
    for (int off = 32; off; off >>= 1) s += __shfl_xor(s, off);
    if (lane == 0) {
        const float lnu = (j < 1024) ? NORM_C : (LOG_MS + NORM_C);
        v[b * ZCOL + j] = lnu - (mx + logf(s));
    }
}

__global__ void sink_out_kernel(const float* __restrict__ Z0, const float* __restrict__ u,
                                const float* __restrict__ v, float* __restrict__ out)
{
    const int j = blockIdx.x * 256 + threadIdx.x;
    const int i = blockIdx.y, b = blockIdx.z;
    if (j < ZCOL) {
        const size_t idx = (size_t)b * ZBAT + (size_t)i * ZCOL + j;
        out[idx] = Z0[idx] + u[b * 257 + i] + v[b * ZCOL + j] + LOG_TOT;
    }
}

// ---------------------------------------------------------------------------
static inline void gemmP64(hipStream_t st,
                           const _Float16* Ph0, const _Float16* Pl0, int S0,
                           const _Float16* Ph1, const _Float16* Pl1, int S1,
                           const float* X0, const float* X1, int C0,
                           const float* bias, const float* res, int Nr,
                           float* out, int No, int O, int C, int N, int relu)
{
    dim3 g(N / 128, O / 64);
    gemm64p_kernel<<<g, 256, 0, st>>>(Ph0, Pl0, S0, Ph1, Pl1, S1, X0, X1,
                                      bias, res, out, O, C, C0, N, Nr, No, relu);
}

extern "C" void kernel_launch(void* const* d_in, const int* in_sizes, int n_in,
                              void* d_out, int out_size, void* d_ws, size_t ws_size,
                              hipStream_t stream)
{
    (void)in_sizes; (void)n_in; (void)out_size; (void)ws_size;
    const float* det_in = (const float*)d_in[0];
    const float* trk_in = (const float*)d_in[1];
    const float* enc_w1 = (const float*)d_in[2];
    const float* enc_b1 = (const float*)d_in[3];
    const float* enc_w2 = (const float*)d_in[4];
    const float* enc_b2 = (const float*)d_in[5];
    const float* fus_pw = (const float*)d_in[6];
    const float* fus_pb = (const float*)d_in[7];
    const float* fus_mw = (const float*)d_in[8];
    const float* fus_mb = (const float*)d_in[9];
    const float* fus_m1w = (const float*)d_in[10];
    const float* fus_m1b = (const float*)d_in[11];
    const float* fus_m2w = (const float*)d_in[12];
    const float* fus_m2b = (const float*)d_in[13];
    const float* gnn_pw = (const float*)d_in[14];
    const float* gnn_pb = (const float*)d_in[15];
    const float* gnn_mw = (const float*)d_in[16];
    const float* gnn_mb = (const float*)d_in[17];
    const float* gnn_m1w = (const float*)d_in[18];
    const float* gnn_m1b = (const float*)d_in[19];
    const float* gnn_m2w = (const float*)d_in[20];
    const float* gnn_m2b = (const float*)d_in[21];
    const float* final_w = (const float*)d_in[22];
    const float* final_b = (const float*)d_in[23];
    const float* bin_sc  = (const float*)d_in[24];
    float* out = (float*)d_out;

    float* ws = (float*)d_ws;
    float* XF   = ws;                      // 4,194,304  fuser state x [256][16384]
    float* R    = ws + 4194304;            // 16,777,216 temp arena
    float* COMB = ws + 20971520;           // 1,310,720  [256][5120] tr|det state
    float* Z0   = ws + 22282240;           // 1,053,700
    float* U    = ws + 23335940;           //     1,028
    float* V    = ws + 23336968;           //     4,100
    // fuser / det-enc arena:
    float* Qf = R;
    float* Kf = R + 4194304;
    float* Vf = R + 8388608;               // fuser only
    float* MS = R + 12582912;              // fuser only
    // GNN arena (N=5120):
    float* QKV = R;                       // [768][5120]
    float* H   = R + 1310720;             // [512][5120] (overlays dead QKV tail)
    float* MSG = R + 3932160;             // [256][5120]
    float* M   = R + 5242880;             // [256][5120]; det-PE before GNN; final proj after
    // attn split-K partials (GNN loop only; overlays M which is dead there):
    _Float16* PO = (_Float16*)(R + 5242880);  // [320*4][64][64] halves = 5,242,880 h
    float* PM = R + 7864320;                  // [320*4][64]
    float* PL = R + 7946240;                  // [320*4][64]; ends 8,028,160 < 8,388,608
    // fused msg-proj weights:
    //   fuser: fp16 planes in COMB region (dead until meanpool)
    _Float16* Whff = (_Float16*)COMB;             // [4][512][256] halves
    _Float16* Wlff = (_Float16*)(COMB + 262144);  // [4][512][256] halves
    float* bcf = COMB + 524288;                   // [4][512]
    //   GNN plane arena: old Vf/MS region (free after fuser; 8.39M floats)
    _Float16* GP   = (_Float16*)(R + 8388608);
    _Float16* gph  = GP;                 // gnn_pw planes: [12][768][256]
    _Float16* gpl  = GP + 2359296;
    _Float16* gm1h = GP + 4718592;       // gnn_m1w x-part: [12][512][256]
    _Float16* gm1l = GP + 6291456;
    _Float16* gm2h = GP + 7864320;       // gnn_m2w: [12][256][512]
    _Float16* gm2l = GP + 9437184;
    _Float16* wfh  = GP + 11010048;      // GNN Wf = m1wB@mw: [12][512][256]
    _Float16* wfl  = GP + 12582912;
    _Float16* fnh  = GP + 14155776;      // final_w: [256][256]
    _Float16* fnl  = GP + 14221312;      // ends 14,286,848 halves
    float* bcg = R + 15600000;           // [12][512]
    float* Z0T = R;                      // sinkhorn transpose (end phase)
    // fp16 hi/lo weight-plane arena (fuser path), in HALVES from base:
    _Float16* PB = (_Float16*)(ws + 23400000);
    _Float16* e1h = PB;              _Float16* e1l = PB + 65536;
    _Float16* e2h = PB + 131072;     _Float16* e2l = PB + 196608;
    _Float16* pwh = PB + 262144;     _Float16* pwl = PB + 1048576;   // 4x196608
    _Float16* m1h = PB + 1835008;    _Float16* m1l = PB + 2883584;   // 4x262144 (full 512-wide)
    _Float16* m2h = PB + 3932160;    _Float16* m2l = PB + 4456448;   // 4x131072

    // ===== weight-plane precompute (independent; before everything) =======
    split_multi_kernel<<<9728, 256, 0, stream>>>(
        enc_w1, e1h, e1l, 256, 0,
        enc_w2, e2h, e2l, 512, 0,
        fus_pw, pwh, pwl, 3584, 0,
        fus_m1w, m1h, m1l, 7680, 0,
        fus_m2w, m2h, m2l, 9728, 0);
    fusewh_kernel<<<dim3(2, 8, 4), 256, 0, stream>>>(fus_m1w, fus_mw, Whff, Wlff);
    fusebias_kernel<<<dim3(2, 4), 256, 0, stream>>>(fus_m1w, fus_mb, fus_m1b, bcf);

    // ================= encoder (tracks) + fuser ===========================
    pe_kernel<<<dim3(NCT/256, 4), 256, 0, stream>>>(trk_in, MS, NCT, 4, 257*16);
    repack_kernel<<<dim3(NCT/256, 256), 256, 0, stream>>>(trk_in, Qf, NCT, 4, 257*16);
    gemmP64(stream, e1h, e1l, 256, e1h, e1l, 256, Qf, Qf, 256,
            enc_b1, nullptr, 0, Kf, NCT, 256, 256, NCT, 1);
    gemmP64(stream, e2h, e2l, 256, e2h, e2l, 256, Kf, Kf, 256,
            enc_b2, MS, NCT, XF, NCT, 256, 256, NCT, 0);

    for (int l = 0; l < 4; ++l) {
        gemmP64(stream, pwh + l*196608, pwl + l*196608, 256,
                pwh, pwl, 256, XF, XF, 256,
                fus_pb + l*768, nullptr, 0, Qf, NCT, 768, 256, NCT, 0);
        fuser_attn_kernel<<<1024, 256, 0, stream>>>(Qf, Kf, Vf, MS);
        gemmP64(stream, m1h + l*262144, m1l + l*262144, 512,
                Whff + l*131072, Wlff + l*131072, 256, XF, MS, 256,
                bcf + l*512, nullptr, 0, Kf, NCT, 512, 512, NCT, 1);
        gemmP64(stream, m2h + l*131072, m2l + l*131072, 512,
                m2h, m2l, 512, Kf, Kf, 512,
                fus_m2b + l*256, XF, NCT, XF, NCT, 256, 512, NCT, 0);
    }

    // ===== GNN plane precompute (old Vf/MS region now free) ===============
    split_multi_kernel<<<21760, 256, 0, stream>>>(
        gnn_pw, gph, gpl, 9216, 0,
        gnn_m1w, gm1h, gm1l, 15360, 512,
        gnn_m2w, gm2h, gm2l, 21504, 0,
        final_w, fnh, fnl, 21760, 0,
        final_w, fnh, fnl, 21760, 0);
    fusewh_kernel<<<dim3(2, 8, 12), 256, 0, stream>>>(gnn_m1w, gnn_mw, wfh, wfl);
    fusebias_kernel<<<dim3(2, 12), 256, 0, stream>>>(gnn_m1w, gnn_mb, gnn_m1b, bcg);

    meanpool_kernel<<<dim3(4, 256), 256, 0, stream>>>(XF, COMB);   // tr cols [0,1024)

    // ================= encoder (detections) -> COMB cols [1024,5120) ======
    pe_kernel<<<dim3(NCD/256, 4), 256, 0, stream>>>(det_in, M, NCD, 10, 257*1024);
    repack_kernel<<<dim3(NCD/256, 256), 256, 0, stream>>>(det_in, Qf, NCD, 10, 257*1024);
    gemmP64(stream, e1h, e1l, 256, e1h, e1l, 256, Qf, Qf, 256,
            enc_b1, nullptr, 0, Kf, NCD, 256, 256, NCD, 1);
    gemmP64(stream, e2h, e2l, 256, e2h, e2l, 256, Kf, Kf, 256,
            enc_b2, M, NCD, COMB + 1024, NCB, 256, 256, NCD, 0);

    // ================= GNN (combined tr|det, N=5120) ======================
    for (int l = 0; l < 12; ++l) {
        const _Float16* lph = gph + l*196608;
        const _Float16* lpl = gpl + l*196608;
        const float* pb  = gnn_pb + l*768;
        const float* m2b = gnn_m2b + l*256;
        const int cross = (l & 1);

        gemmP64(stream, lph, lpl, 256, lph, lpl, 256, COMB, COMB, 256,
                pb, nullptr, 0, QKV, NCB, 768, 256, NCB, 0);
        attn2_kernel<<<dim3(80, 4, 4), 256, 0, stream>>>(QKV, PO, PM, PL, cross);
        attn_merge_kernel<<<dim3(20, 4, 4), 256, 0, stream>>>(PO, PM, PL, MSG);
        gemmP64(stream, gm1h + l*131072, gm1l + l*131072, 256,
                wfh + l*131072, wfl + l*131072, 256, COMB, MSG, 256,
                bcg + l*512, nullptr, 0, H, NCB, 512, 512, NCB, 1);
        gemmP64(stream, gm2h + l*131072, gm2l + l*131072, 512,
                gm2h + l*131072, gm2l + l*131072, 512, H, H, 512,
                m2b, COMB, NCB, COMB, NCB, 256, 512, NCB, 0);
    }

    // ================= final projection + scores + sinkhorn ===============
    gemmP64(stream, fnh, fnl, 256, fnh, fnl, 256, COMB, COMB, 256,
            final_b, nullptr, 0, M, NCB, 256, 256, NCB, 0);
    scores_kernel<<<dim3(16, 4, 4), 256, 0, stream>>>(M, Z0, Z0T);
    sink_init_kernel<<<21, 256, 0, stream>>>(Z0, Z0T, V, bin_sc);
    for (int it = 0; it < SINK_IT; ++it) {
        sink_u_kernel<<<257, 256, 0, stream>>>(Z0, V, U);
        sink_v_kernel<<<1025, 256, 0, stream>>>(Z0T, U, V);
    }
    sink_out_kernel<<<dim3(5, 257, 4), 256, 0, stream>>>(Z0, U, V, out);
}

// Round 14
// 2397.302 us; speedup vs baseline: 1.0867x; 1.0458x over previous
//
#include <hip/hip_runtime.h>
#include <math.h>

// ---------------------------------------------------------------------------
// Associator forward (R13): FP16 ACTIVATIONS END-TO-END. All intermediate
// activation buffers fp16 in HBM (R12 insight: every consumer rounds to fp16
// at staging anyway -> fp32 storage = 2x traffic + cvt chains for nothing).
// GEMM: A-hi plane (16B DMA->LDS) x B fp16 (f16x4 load + register repack,
// ZERO converts), fp32 acc, fp16 out. Residuals fp32-accumulated, rounded
// once/layer (~5e-4). attn2: flash SPLIT-K (S=4), all-fp16 operands (Q now
// born fp16 -> lo plane gone, QK MFMA halved), no staging converts.
// Sinkhorn: fp32, 60 iters x 2 micro-launches (launch-bound; persistent
// barrier ~20us/barrier = 2x worse R5; fp16 Z0 = null R7).
// ---------------------------------------------------------------------------

#define NCT 16384
#define NCD 4096
#define NCB 5120
#define ZROW 257
#define ZCOL 1025
#define ZBAT (ZROW*ZCOL)   // 263425

#define SINK_IT 60

#define NORM_C  (-7.1546153569f)   // -log(1280)
#define LOG_NS  (6.9314718056f)    // log(1024)
#define LOG_MS  (5.5451774445f)    // log(256)
#define LOG_TOT (7.1546153569f)    // +log(1280)

typedef _Float16 f16x8 __attribute__((ext_vector_type(8)));
typedef _Float16 f16x4 __attribute__((ext_vector_type(4)));
typedef float f32x4 __attribute__((ext_vector_type(4)));

#define APAD 40   // LDS row stride in halves for B tiles (80 B; 2-way banks)

// 16B global->LDS stage. DMA path: per-lane global addr g, wave-uniform LDS
// base; HW places lane i at base + 16i. Fallback reproduces the placement.
__device__ __forceinline__ void stage16(const _Float16* g, _Float16* ldsbase, int lane)
{
#if __has_builtin(__builtin_amdgcn_global_load_lds)
    __builtin_amdgcn_global_load_lds(
        (const __attribute__((address_space(1))) unsigned int*)(const void*)g,
        (__attribute__((address_space(3))) unsigned int*)(void*)ldsbase, 16, 0, 0);
#else
    *(f16x8*)(ldsbase + lane * 8) = *(const f16x8*)g;
#endif
}

// ---------------- GEMM 64x128 tile (ALL gemms; fp16 A,B; fp16 out) ---------
// out = [W0|W1] @ [X0;X1] + bias (+res) (relu?). A-side from fp16 hi plane:
// k<C0 from Ph0 (stride S0 halves), k>=C0 from Ph1 (stride S1).
// B-side fp16 activations: f16x4 loads, register repack, no converts.
__global__ __launch_bounds__(256) void gemm64p_kernel(
    const _Float16* __restrict__ Ph0, const _Float16* __restrict__ Pl0, int S0,
    const _Float16* __restrict__ Ph1, const _Float16* __restrict__ Pl1, int S1,
    const _Float16* __restrict__ X0, const _Float16* __restrict__ X1,
    const float* __restrict__ bias, const _Float16* __restrict__ res,
    _Float16* __restrict__ out,
    int O, int C, int C0, int N, int Nr, int No, int relu)
{
    __shared__ _Float16 Ah[64][32];
    __shared__ _Float16 Bh[128][APAD];
    const int tid = threadIdx.x;
    const int n0 = blockIdx.x * 128, m0 = blockIdx.y * 64;
    const int wave = tid >> 6, lane = tid & 63;
    const int wo = (wave >> 1) * 32, wn = (wave & 1) * 64;
    const int lm = lane & 15, lq = lane >> 4;
    // A DMA swizzle: slot s of row R holds k-chunk s ^ ((R>>1)&3); lane
    // fetches chunk (i&3)^((i>>3)&3); read uses slot lq^((R>>1)&3).
    const int sar = lane >> 2;
    const int sakx = ((lane & 3) ^ ((lane >> 3) & 3)) * 8;
    const int asw = (lq ^ ((lm >> 1) & 3)) * 8;
    const int bkg = tid & 7, bng = tid >> 3;

    f32x4 acc[2][4] = {};

    for (int kb = 0; kb < C; kb += 32) {
        f16x4 xv[4];
        #pragma unroll
        for (int r = 0; r < 4; ++r) {
            const int krow = kb + bkg * 4 + r;
            const _Float16* xs = (krow < C0) ? X0 + (size_t)krow * N
                                             : X1 + (size_t)(krow - C0) * N;
            xv[r] = *(const f16x4*)(xs + n0 + bng * 4);
        }
        const bool s0 = (kb < C0);
        const _Float16* ph = s0 ? Ph0 : Ph1;
        const int S = s0 ? S0 : S1;
        const int kc = s0 ? kb : kb - C0;
        __syncthreads();
        // ---- A: 16B DMA of hi plane (one instr per wave) ----
        {
            const int r0 = wave * 16;
            const size_t go = (size_t)(m0 + r0 + sar) * S + kc + sakx;
            stage16(ph + go, &Ah[r0][0], lane);
        }
        // ---- B: register repack (transpose), no converts ----
        #pragma unroll
        for (int j = 0; j < 4; ++j) {
            _Float16 hb[4];
            #pragma unroll
            for (int r = 0; r < 4; ++r) hb[r] = xv[r][j];
            *(f16x4*)&Bh[bng * 4 + j][bkg * 4] = *(const f16x4*)&hb[0];
        }
        __syncthreads();
        f16x8 bh[4];
        #pragma unroll
        for (int t = 0; t < 4; ++t)
            bh[t] = *(const f16x8*)&Bh[wn + t * 16 + lm][lq * 8];
        #pragma unroll
        for (int mt = 0; mt < 2; ++mt) {
            const f16x8 ah = *(const f16x8*)&Ah[wo + mt * 16 + lm][asw];
            #pragma unroll
            for (int nt = 0; nt < 4; ++nt)
                acc[mt][nt] = __builtin_amdgcn_mfma_f32_16x16x32_f16(ah, bh[nt], acc[mt][nt], 0, 0, 0);
        }
    }
    #pragma unroll
    for (int mt = 0; mt < 2; ++mt) {
        #pragma unroll
        for (int rg = 0; rg < 4; ++rg) {
            const int o = m0 + wo + mt * 16 + lq * 4 + rg;
            const float bs = bias[o];
            #pragma unroll
            for (int nt = 0; nt < 4; ++nt) {
                const int n = n0 + wn + nt * 16 + lm;
                float v = acc[mt][nt][rg] + bs;
                if (res) v += (float)res[(size_t)o * Nr + n];
                if (relu) v = fmaxf(v, 0.f);
                out[(size_t)o * No + n] = (_Float16)v;
            }
        }
    }
}

// ---------------- merged weight split: fp32 -> fp16 hi/lo planes -----------
__global__ void split_multi_kernel(
    const float* __restrict__ s0, _Float16* __restrict__ h0, _Float16* __restrict__ l0, int c0, int st0,
    const float* __restrict__ s1, _Float16* __restrict__ h1, _Float16* __restrict__ l1, int c1, int st1,
    const float* __restrict__ s2, _Float16* __restrict__ h2, _Float16* __restrict__ l2, int c2, int st2,
    const float* __restrict__ s3, _Float16* __restrict__ h3, _Float16* __restrict__ l3, int c3, int st3,
    const float* __restrict__ s4, _Float16* __restrict__ h4, _Float16* __restrict__ l4, int c4, int st4)
{
    int b = blockIdx.x;
    const float* s; _Float16* h; _Float16* l; int st;
    if      (b < c0) {               s = s0; h = h0; l = l0; st = st0; }
    else if (b < c1) { b -= c0;      s = s1; h = h1; l = l1; st = st1; }
    else if (b < c2) { b -= c1;      s = s2; h = h2; l = l2; st = st2; }
    else if (b < c3) { b -= c2;      s = s3; h = h3; l = l3; st = st3; }
    else             { b -= c3;      s = s4; h = h4; l = l4; st = st4; }
    const int i = b * 256 + threadIdx.x;
    const float x = st ? s[(size_t)(i >> 8) * st + (i & 255)] : s[i];
    const _Float16 hh = (_Float16)x;
    h[i] = hh;
    l[i] = (_Float16)(x - (float)hh);
}

// ---------------- batched Wf = m1wB @ mw, fp16-plane out -------------------
__global__ __launch_bounds__(256) void fusewh_kernel(
    const float* __restrict__ m1w_base, const float* __restrict__ mw_base,
    _Float16* __restrict__ wfh_base, _Float16* __restrict__ wfl_base)
{
    const int z = blockIdx.z;
    const float* A = m1w_base + (size_t)z * 262144 + 256;
    const float* B = mw_base + (size_t)z * 65536;
    _Float16* oh = wfh_base + (size_t)z * 131072;
    _Float16* ol = wfl_base + (size_t)z * 131072;
    __shared__ _Float16 Ah[64][APAD], Al[64][APAD];
    __shared__ _Float16 Bh[128][APAD], Bl[128][APAD];
    const int tid = threadIdx.x;
    const int n0 = blockIdx.x * 128, m0 = blockIdx.y * 64;
    const int wave = tid >> 6, lane = tid & 63;
    const int wo = (wave >> 1) * 32, wn = (wave & 1) * 64;
    const int lm = lane & 15, lq = lane >> 4;
    const int ar = tid >> 2, ak8 = (tid & 3) << 3;
    const int bkg = tid & 7, bng = tid >> 3;

    f32x4 acc[2][4] = {};
    for (int kb = 0; kb < 256; kb += 32) {
        float4 av[2];
        const float* wp = A + (size_t)(m0 + ar) * 512 + kb + ak8;
        av[0] = *(const float4*)(wp);
        av[1] = *(const float4*)(wp + 4);
        float4 xv[4];
        #pragma unroll
        for (int r = 0; r < 4; ++r)
            xv[r] = *(const float4*)(B + (size_t)(kb + bkg * 4 + r) * 256 + n0 + bng * 4);
        __syncthreads();
        {
            _Float16 hbuf[8], lbuf[8];
            #pragma unroll
            for (int q = 0; q < 2; ++q) {
                const float* f = (const float*)&av[q];
                #pragma unroll
                for (int c = 0; c < 4; ++c) {
                    const float x = f[c];
                    const _Float16 h = (_Float16)x;
                    hbuf[q * 4 + c] = h;
                    lbuf[q * 4 + c] = (_Float16)(x - (float)h);
                }
            }
            *(f16x8*)&Ah[ar][ak8] = *(const f16x8*)&hbuf[0];
            *(f16x8*)&Al[ar][ak8] = *(const f16x8*)&lbuf[0];
        }
        #pragma unroll
        for (int j = 0; j < 4; ++j) {
            _Float16 hb[4], lb[4];
            #pragma unroll
            for (int r = 0; r < 4; ++r) {
                const float x = ((const float*)&xv[r])[j];
                const _Float16 h = (_Float16)x;
                hb[r] = h;
                lb[r] = (_Float16)(x - (float)h);
            }
            *(f16x4*)&Bh[bng * 4 + j][bkg * 4] = *(const f16x4*)&hb[0];
            *(f16x4*)&Bl[bng * 4 + j][bkg * 4] = *(const f16x4*)&lb[0];
        }
        __syncthreads();
        f16x8 bh[4], bl[4];
        #pragma unroll
        for (int t = 0; t < 4; ++t) {
            bh[t] = *(const f16x8*)&Bh[wn + t * 16 + lm][lq * 8];
            bl[t] = *(const f16x8*)&Bl[wn + t * 16 + lm][lq * 8];
        }
        #pragma unroll
        for (int mt = 0; mt < 2; ++mt) {
            const f16x8 ah = *(const f16x8*)&Ah[wo + mt * 16 + lm][lq * 8];
            const f16x8 al = *(const f16x8*)&Al[wo + mt * 16 + lm][lq * 8];
            #pragma unroll
            for (int nt = 0; nt < 4; ++nt) {
                acc[mt][nt] = __builtin_amdgcn_mfma_f32_16x16x32_f16(ah, bh[nt], acc[mt][nt], 0, 0, 0);
                acc[mt][nt] = __builtin_amdgcn_mfma_f32_16x16x32_f16(ah, bl[nt], acc[mt][nt], 0, 0, 0);
                acc[mt][nt] = __builtin_amdgcn_mfma_f32_16x16x32_f16(al, bh[nt], acc[mt][nt], 0, 0, 0);
            }
        }
    }
    #pragma unroll
    for (int mt = 0; mt < 2; ++mt)
        #pragma unroll
        for (int rg = 0; rg < 4; ++rg) {
            const int o = m0 + wo + mt * 16 + lq * 4 + rg;
            #pragma unroll
            for (int nt = 0; nt < 4; ++nt) {
                const float v = acc[mt][nt][rg];
                const _Float16 hh = (_Float16)v;
                oh[(size_t)o * 256 + n0 + wn + nt * 16 + lm] = hh;
                ol[(size_t)o * 256 + n0 + wn + nt * 16 + lm] = (_Float16)(v - (float)hh);
            }
        }
}

// ---------------- batched bc = m1wB @ mb + m1b -----------------------------
__global__ void fusebias_kernel(const float* __restrict__ m1w_base,
                                const float* __restrict__ mb_base,
                                const float* __restrict__ m1b_base,
                                float* __restrict__ bc_base)
{
    const int z = blockIdx.y;
    const int o = blockIdx.x * 256 + threadIdx.x;   // 0..511
    const float* A = m1w_base + (size_t)z * 262144 + (size_t)o * 512 + 256;
    const float* mb = mb_base + z * 256;
    float s = m1b_base[z * 512 + o];
    for (int c = 0; c < 256; ++c) s = fmaf(A[c], mb[c], s);
    bc_base[z * 512 + o] = s;
}

// ---------------- positional encoding -> fp16 ------------------------------
__global__ void pe_kernel(const float* __restrict__ src, _Float16* __restrict__ pe,
                          int N, int shift, int cstride)
{
    const int col = blockIdx.x * 256 + threadIdx.x;
    if (col >= N) return;
    const int seg = 1 << shift;
    const int i0 = blockIdx.y * 32;
    const float pos = src[(size_t)(col >> shift) * cstride + (col & (seg - 1))];
    #pragma unroll 4
    for (int i = i0; i < i0 + 32; ++i) {
        const float div = expf((float)i * -0.07195578415606394f); // -ln(10000)/128
        const float ang = pos * div;
        pe[(size_t)(2*i) * N + col]   = (_Float16)sinf(ang);
        pe[(size_t)(2*i+1) * N + col] = (_Float16)cosf(ang);
    }
}

// ---------------- input repack (drop channel 0) -> fp16 --------------------
__global__ void repack_kernel(const float* __restrict__ src, _Float16* __restrict__ dst,
                              int N, int shift, int cstride)
{
    const int col = blockIdx.x * 256 + threadIdx.x;
    const int c = blockIdx.y;
    if (col >= N) return;
    const int seg = 1 << shift;
    dst[(size_t)c * N + col] = (_Float16)
        src[(size_t)(col >> shift) * cstride + (size_t)(c + 1) * seg + (col & (seg - 1))];
}

// ---------------- fuser self-attention over time (n=m=16 per track) -------
__global__ __launch_bounds__(256) void fuser_attn_kernel(
    const _Float16* __restrict__ Qb, const _Float16* __restrict__ Kb,
    const _Float16* __restrict__ Vb, _Float16* __restrict__ Ob)
{
    __shared__ float qs[256][17], ks[256][17], vs[256][17];
    __shared__ float ps[4][16][17];
    const int trk = blockIdx.x, tid = threadIdx.x;
    const int col0 = trk * 16;
    for (int idx = tid; idx < 1024; idx += 256) {
        const int r = idx >> 2, seg = (idx & 3) << 2;
        const f16x4 q = *(const f16x4*)&Qb[(size_t)r * NCT + col0 + seg];
        const f16x4 k = *(const f16x4*)&Kb[(size_t)r * NCT + col0 + seg];
        const f16x4 v = *(const f16x4*)&Vb[(size_t)r * NCT + col0 + seg];
        #pragma unroll
        for (int i = 0; i < 4; ++i) {
            qs[r][seg+i] = (float)q[i];
            ks[r][seg+i] = (float)k[i];
            vs[r][seg+i] = (float)v[i];
        }
    }
    __syncthreads();
    {
        const int g = tid >> 2, h = g >> 4, n = g & 15, mb = (tid & 3) << 2;
        float s[4] = {};
        #pragma unroll 4
        for (int hd = 0; hd < 64; ++hd) {
            const int c = hd*4 + h;
            const float q = qs[c][n];
            #pragma unroll
            for (int j = 0; j < 4; ++j) s[j] = fmaf(q, ks[c][mb + j], s[j]);
        }
        #pragma unroll
        for (int j = 0; j < 4; ++j) ps[h][n][mb + j] = s[j] * 0.125f;
    }
    __syncthreads();
    if (tid < 64) {
        const int hh = tid >> 4, nn = tid & 15;
        float mx = -INFINITY;
        for (int m = 0; m < 16; ++m) mx = fmaxf(mx, ps[hh][nn][m]);
        float sum = 0.f;
        for (int m = 0; m < 16; ++m) { const float p = expf(ps[hh][nn][m] - mx);
                                       ps[hh][nn][m] = p; sum += p; }
        const float inv = 1.f / sum;
        for (int m = 0; m < 16; ++m) ps[hh][nn][m] *= inv;
    }
    __syncthreads();
    {
        const int c = tid, hc = c & 3;
        float msg[16];
        #pragma unroll
        for (int n = 0; n < 16; ++n) {
            float a = 0.f;
            #pragma unroll
            for (int m = 0; m < 16; ++m) a = fmaf(ps[hc][n][m], vs[c][m], a);
            msg[n] = a;
        }
        __syncthreads();
        #pragma unroll
        for (int n = 0; n < 16; ++n) qs[c][n] = msg[n];
    }
    __syncthreads();
    for (int idx = tid; idx < 1024; idx += 256) {
        const int r = idx >> 2, seg = (idx & 3) << 2;
        _Float16 o4[4];
        #pragma unroll
        for (int i = 0; i < 4; ++i) o4[i] = (_Float16)qs[r][seg+i];
        *(f16x4*)&Ob[(size_t)r * NCT + col0 + seg] = *(const f16x4*)o4;
    }
}

// ---------------- GNN attention: fp16 flash, SPLIT-K (S=4) -----------------
// grid.x = 80: nt_raw = x>>2 (LPT remap), s = x&3 -> m-tiles [s*cnt, ...).
// ALL operands fp16 (QKV stored fp16): no staging converts, QK 1 MFMA/frag.
// Writes unnormalized partials: PO fp16, PM/PL fp32.
__global__ __launch_bounds__(256) void attn2_kernel(
    const _Float16* __restrict__ QKV, _Float16* __restrict__ PO,
    float* __restrict__ PM, float* __restrict__ PL, int cross)
{
    __shared__ _Float16 SH[2][64][72];
    _Float16 (*Kh)[72] = SH[0];   // K; P after QK; Q at start
    _Float16 (*Vh)[72] = SH[1];   // V
    const int b = blockIdx.z, h = blockIdx.y;
    const int raw = blockIdx.x;
    const int sp = raw & 3;
    const int nt_raw = raw >> 2;
    const int nt = cross ? nt_raw : ((nt_raw < 16) ? (nt_raw + 4) : (nt_raw - 16));
    const _Float16* Qb = QKV;
    const _Float16* Kb = QKV + (size_t)256 * NCB;
    const _Float16* Vb = QKV + (size_t)512 * NCB;
    int qcol, kbase, nk;
    if (nt < 4) {
        qcol = b * 256 + nt * 64;
        if (cross) { kbase = 1024 + b * 1024; nk = 1024; }
        else       { kbase = b * 256;         nk = 256;  }
    } else {
        qcol = 1024 + b * 1024 + (nt - 4) * 64;
        if (cross) { kbase = b * 256;         nk = 256;  }
        else       { kbase = 1024 + b * 1024; nk = 1024; }
    }
    const int tid = threadIdx.x;
    const int wave = tid >> 6, lane = tid & 63;
    const int lm = lane & 15, quad = lane >> 4;
    const int dg = tid & 15, qg = tid >> 4;
    const int vd = tid >> 2, vseg = (tid & 3) * 16;
    const int vchan = vd * 4 + h;

    // ---- Q stage (into Kh) + consume to regs ----
    {
        f16x4 xv[4];
        #pragma unroll
        for (int r = 0; r < 4; ++r) {
            const int chan = (dg * 4 + r) * 4 + h;
            xv[r] = *(const f16x4*)&Qb[(size_t)chan * NCB + qcol + qg * 4];
        }
        #pragma unroll
        for (int j = 0; j < 4; ++j) {
            _Float16 hb[4];
            #pragma unroll
            for (int r = 0; r < 4; ++r) hb[r] = xv[r][j];
            *(f16x4*)&Kh[qg * 4 + j][dg * 4] = *(const f16x4*)hb;
        }
    }
    __syncthreads();
    f16x8 qh[2];
    #pragma unroll
    for (int ks = 0; ks < 2; ++ks)
        qh[ks] = *(const f16x8*)&Kh[wave * 16 + lm][ks * 32 + quad * 8];

    float rmax[4], rsum[4];
    #pragma unroll
    for (int r = 0; r < 4; ++r) { rmax[r] = -INFINITY; rsum[r] = 0.f; }
    f32x4 acco[4] = {};

    const int mtn = nk >> 6;
    const int cnt = mtn >> 2;       // S=4 parts
    const int mt0 = sp * cnt;
    const int mtE = mt0 + cnt;
    f16x4 kxv[4];
    f16x8 vxv[2];
    {
        const int kcol = kbase + mt0 * 64;
        #pragma unroll
        for (int r = 0; r < 4; ++r) {
            const int chan = (dg * 4 + r) * 4 + h;
            kxv[r] = *(const f16x4*)&Kb[(size_t)chan * NCB + kcol + qg * 4];
        }
        #pragma unroll
        for (int q = 0; q < 2; ++q)
            vxv[q] = *(const f16x8*)&Vb[(size_t)vchan * NCB + kcol + vseg + q * 8];
    }
    for (int mt = mt0; mt < mtE; ++mt) {
        __syncthreads();   // prior tile's (or Q's) fragment reads complete
        // ---- K repack+store (no converts) ----
        #pragma unroll
        for (int j = 0; j < 4; ++j) {
            _Float16 hb[4];
            #pragma unroll
            for (int r = 0; r < 4; ++r) hb[r] = kxv[r][j];
            *(f16x4*)&Kh[qg * 4 + j][dg * 4] = *(const f16x4*)hb;
        }
        // ---- V direct store ----
        *(f16x8*)&Vh[vd][vseg]     = vxv[0];
        *(f16x8*)&Vh[vd][vseg + 8] = vxv[1];
        __syncthreads();
        // ---- issue next tile's loads (overlap QK+softmax+PV below) ----
        if (mt + 1 < mtE) {
            const int kcol = kbase + (mt + 1) * 64;
            #pragma unroll
            for (int r = 0; r < 4; ++r) {
                const int chan = (dg * 4 + r) * 4 + h;
                kxv[r] = *(const f16x4*)&Kb[(size_t)chan * NCB + kcol + qg * 4];
            }
            #pragma unroll
            for (int q = 0; q < 2; ++q)
                vxv[q] = *(const f16x8*)&Vb[(size_t)vchan * NCB + kcol + vseg + q * 8];
        }
        // ---- QK: 1 MFMA per frag pair ----
        f32x4 accs[4] = {};
        #pragma unroll
        for (int t = 0; t < 4; ++t) {
            #pragma unroll
            for (int ks = 0; ks < 2; ++ks) {
                const f16x8 kh = *(const f16x8*)&Kh[t * 16 + lm][ks * 32 + quad * 8];
                accs[t] = __builtin_amdgcn_mfma_f32_16x16x32_f16(qh[ks], kh, accs[t], 0,0,0);
            }
        }
        float alpha[4];
        float psv[4][4];
        #pragma unroll
        for (int r = 0; r < 4; ++r) {
            float mx = fmaxf(fmaxf(accs[0][r], accs[1][r]),
                             fmaxf(accs[2][r], accs[3][r])) * 0.125f;
            #pragma unroll
            for (int off = 1; off < 16; off <<= 1) mx = fmaxf(mx, __shfl_xor(mx, off));
            const float mnew = fmaxf(rmax[r], mx);
            alpha[r] = expf(rmax[r] - mnew);
            rmax[r] = mnew;
            float s = 0.f;
            #pragma unroll
            for (int t = 0; t < 4; ++t) {
                const float p = expf(accs[t][r] * 0.125f - mnew);
                psv[t][r] = p; s += p;
            }
            #pragma unroll
            for (int off = 1; off < 16; off <<= 1) s += __shfl_xor(s, off);
            rsum[r] = rsum[r] * alpha[r] + s;
        }
        __syncthreads();
        // ---- P store (into Kh) ----
        #pragma unroll
        for (int t = 0; t < 4; ++t)
            #pragma unroll
            for (int r = 0; r < 4; ++r)
                Kh[wave * 16 + quad * 4 + r][t * 16 + lm] = (_Float16)psv[t][r];
        __syncthreads();
        #pragma unroll
        for (int td = 0; td < 4; ++td)
            #pragma unroll
            for (int r = 0; r < 4; ++r) acco[td][r] *= alpha[r];
        // ---- PV: 1 MFMA per frag pair ----
        #pragma unroll
        for (int ks = 0; ks < 2; ++ks) {
            const f16x8 ph = *(const f16x8*)&Kh[wave * 16 + lm][ks * 32 + quad * 8];
            #pragma unroll
            for (int td = 0; td < 4; ++td) {
                const f16x8 vh = *(const f16x8*)&Vh[td * 16 + lm][ks * 32 + quad * 8];
                acco[td] = __builtin_amdgcn_mfma_f32_16x16x32_f16(ph, vh, acco[td], 0,0,0);
            }
        }
    }
    // ---- write partials (unnormalized acc + m/l per q-row) ----
    const int qt = ((b * 4 + h) * 20 + nt);
    _Float16* po = PO + ((size_t)(qt * 4 + sp) * 64) * 64;
    #pragma unroll
    for (int td = 0; td < 4; ++td)
        #pragma unroll
        for (int r = 0; r < 4; ++r)
            po[(wave * 16 + quad * 4 + r) * 64 + td * 16 + lm] = (_Float16)acco[td][r];
    if (lm == 0) {
        #pragma unroll
        for (int r = 0; r < 4; ++r) {
            const int qrow = wave * 16 + quad * 4 + r;
            PM[(qt * 4 + sp) * 64 + qrow] = rmax[r];
            PL[(qt * 4 + sp) * 64 + qrow] = rsum[r];
        }
    }
}

// ---------------- flash merge of S=4 attn partials -> MSG (fp16) ----------
__global__ __launch_bounds__(256) void attn_merge_kernel(
    const _Float16* __restrict__ PO, const float* __restrict__ PM,
    const float* __restrict__ PL, _Float16* __restrict__ MSG)
{
    const int b = blockIdx.z, h = blockIdx.y, nt = blockIdx.x;   // logical nt
    const int qcol = (nt < 4) ? (b * 256 + nt * 64) : (1024 + b * 1024 + (nt - 4) * 64);
    const int qt = ((b * 4 + h) * 20 + nt);
    const int tid = threadIdx.x;
    const int qp = tid & 63, cg = tid >> 6;
    float w[4];
    float mg = -INFINITY;
    #pragma unroll
    for (int s = 0; s < 4; ++s) { w[s] = PM[(qt * 4 + s) * 64 + qp]; mg = fmaxf(mg, w[s]); }
    float l = 0.f;
    #pragma unroll
    for (int s = 0; s < 4; ++s) {
        w[s] = expf(w[s] - mg);
        l += w[s] * PL[(qt * 4 + s) * 64 + qp];
    }
    const float invl = 1.f / l;
    f16x8 a0[4], a1[4];
    #pragma unroll
    for (int s = 0; s < 4; ++s) {
        const _Float16* base = PO + (((size_t)(qt * 4 + s) * 64 + qp) * 64 + cg * 16);
        a0[s] = *(const f16x8*)base;
        a1[s] = *(const f16x8*)(base + 8);
    }
    #pragma unroll
    for (int i = 0; i < 8; ++i) {
        float o = 0.f;
        #pragma unroll
        for (int s = 0; s < 4; ++s) o += w[s] * (float)a0[s][i];
        const int d = cg * 16 + i;
        MSG[(size_t)(d * 4 + h) * NCB + qcol + qp] = (_Float16)(o * invl);
    }
    #pragma unroll
    for (int i = 0; i < 8; ++i) {
        float o = 0.f;
        #pragma unroll
        for (int s = 0; s < 4; ++s) o += w[s] * (float)a1[s][i];
        const int d = cg * 16 + 8 + i;
        MSG[(size_t)(d * 4 + h) * NCB + qcol + qp] = (_Float16)(o * invl);
    }
}

// ---------------- mean pool over time (fp16 in/out) ------------------------
__global__ void meanpool_kernel(const _Float16* __restrict__ x, _Float16* __restrict__ tr)
{
    const int trk = blockIdx.x * 256 + threadIdx.x;
    const int d = blockIdx.y;
    const _Float16* p = x + (size_t)d * NCT + (size_t)trk * 16;
    float s = 0.f;
    #pragma unroll
    for (int t = 0; t < 16; ++t) s += (float)p[t];
    tr[(size_t)d * NCB + trk] = (_Float16)(s * 0.0625f);
}

// ---------------- scores = m0^T m1 / 16 into Z0 and Z0T (M fp16) ----------
__global__ __launch_bounds__(256) void scores_kernel(
    const _Float16* __restrict__ M, float* __restrict__ Z0, float* __restrict__ Z0T)
{
    __shared__ float As[8][68];
    __shared__ float Bs[8][68];
    const int bm = blockIdx.x, bn = blockIdx.y, b = blockIdx.z;
    const int tid = threadIdx.x;
    const int n0 = bn * 64, mm0 = bm * 64;
    const int tx = tid & 15, ty = tid >> 4;
    float acc[4][4] = {};
    for (int kb = 0; kb < 256; kb += 8) {
        __syncthreads();
        for (int idx = tid; idx < 512; idx += 256) {
            const int r = idx >> 6, cc = idx & 63;
            As[r][cc] = (float)M[(size_t)(kb + r) * NCB + b * 256 + n0 + cc];
            Bs[r][cc] = (float)M[(size_t)(kb + r) * NCB + 1024 + b * 1024 + mm0 + cc];
        }
        __syncthreads();
        #pragma unroll
        for (int kk = 0; kk < 8; ++kk) {
            float a[4], bv[4];
            #pragma unroll
            for (int i = 0; i < 4; ++i) { a[i] = As[kk][ty*4 + i]; bv[i] = Bs[kk][tx*4 + i]; }
            #pragma unroll
            for (int i = 0; i < 4; ++i)
                #pragma unroll
                for (int j = 0; j < 4; ++j) acc[i][j] = fmaf(a[i], bv[j], acc[i][j]);
        }
    }
    #pragma unroll
    for (int i = 0; i < 4; ++i)
        #pragma unroll
        for (int j = 0; j < 4; ++j) {
            const float s = acc[i][j] * 0.0625f;
            const int rr = n0 + ty*4 + i, cc = mm0 + tx*4 + j;
            Z0 [(size_t)b * ZBAT + (size_t)rr * ZCOL + cc] = s;
            Z0T[(size_t)b * ZBAT + (size_t)cc * ZROW + rr] = s;
        }
}

// ---------------- sinkhorn ------------------------------------------------
__global__ void sink_init_kernel(float* __restrict__ Z0, float* __restrict__ Z0T,
                                 float* __restrict__ v, const float* __restrict__ binp)
{
    const float alpha = binp[0];
    const int idx = blockIdx.x * 256 + threadIdx.x;
    if (idx < 4 * ZCOL) v[idx] = 0.f;
    if (idx < 4 * 1281) {
        const int b = idx / 1281, e = idx % 1281;
        if (e < 1025) Z0[(size_t)b * ZBAT + 256 * ZCOL + e] = alpha;
        else          Z0[(size_t)b * ZBAT + (size_t)(e - 1025) * ZCOL + 1024] = alpha;
    }
    if (idx < 4 * 1282) {
        const int b = idx / 1282, e = idx % 1282;
        if (e < 257) Z0T[(size_t)b * ZBAT + 1024 * ZROW + e] = alpha;
        else         Z0T[(size_t)b * ZBAT + (size_t)(e - 257) * ZROW + 256] = alpha;
    }
}

__global__ __launch_bounds__(256) void sink_u_kernel(
    const float* __restrict__ Z0, const float* __restrict__ v, float* __restrict__ u)
{
    const int w = threadIdx.x >> 6, lane = threadIdx.x & 63;
    const int row = blockIdx.x * 4 + w;          // 0..1027
    const int b = row / 257, i = row % 257;
    const float* z  = Z0 + (size_t)b * ZBAT + (size_t)i * ZCOL;
    const float* vb = v + b * ZCOL;
    float zz[17];
    float mx = -INFINITY;
    #pragma unroll
    for (int k = 0; k < 16; ++k) {
        zz[k] = z[lane + k*64] + vb[lane + k*64];
        mx = fmaxf(mx, zz[k]);
    }
    zz[16] = (lane == 0) ? (z[1024] + vb[1024]) : -INFINITY;
    mx = fmaxf(mx, zz[16]);
    #pragma unroll
    for (int off = 32; off; off >>= 1) mx = fmaxf(mx, __shfl_xor(mx, off));
    float s = 0.f;
    #pragma unroll
    for (int k = 0; k < 17; ++k) s += expf(zz[k] - mx);
    #pragma unroll
    for (int off = 32; off; off >>= 1) s += __shfl_xor(s, off);
    if (lane == 0) {
        const float lmu = (i < 256) ? NORM_C : (LOG_NS + NORM_C);
        u[b * 257 + i] = lmu - (mx + logf(s));
    }
}

__global__ __launch_bounds__(256) void sink_v_kernel(
    const float* __restrict__ Z0T, const float* __restrict__ u, float* __restrict__ v)
{
    const int w = threadIdx.x >> 6, lane = threadIdx.x & 63;
    const int row = blockIdx.x * 4 + w;          // 0..4099
    const int b = row / 1025, j = row - b * 1025;
    const float* z  = Z0T + (size_t)b * ZBAT + (size_t)j * ZROW;
    const float* ub = u + b * 257;
    float zz[5];
    float mx = -INFINITY;
    #pragma unroll
    for (int k = 0; k < 4; ++k) {
        zz[k] = z[lane + k*64] + ub[lane + k*64];
        mx = fmaxf(mx, zz[k]);
    }
    zz[4] = (lane == 0) ? (z[256] + ub[256]) : -INFINITY;
    mx = fmaxf(mx, zz[4]);
    #pragma unroll
    for (int off = 32; off; off >>= 1) mx = fmaxf(mx, __shfl_xor(mx, off));
    float s = 0.f;
    #pragma unroll
    for (int k = 0; k < 5; ++k) s += expf(zz[k] - mx);
    #pragma unroll
    for (int off = 32; off; off >>= 1) s += __shfl_xor(s, off);
    if (lane == 0) {
        const float lnu = (j < 1024) ? NORM_C : (LOG_MS + NORM_C);
        v[b * ZCOL + j] = lnu - (mx + logf(s));
    }
}

__global__ void sink_out_kernel(const float* __restrict__ Z0, const float* __restrict__ u,
                                const float* __restrict__ v, float* __restrict__ out)
{
    const int j = blockIdx.x * 256 + threadIdx.x;
    const int i = blockIdx.y, b = blockIdx.z;
    if (j < ZCOL) {
        const size_t idx = (size_t)b * ZBAT + (size_t)i * ZCOL + j;
        out[idx] = Z0[idx] + u[b * 257 + i] + v[b * ZCOL + j] + LOG_TOT;
    }
}

// ---------------------------------------------------------------------------
static inline void gemmP64(hipStream_t st,
                           const _Float16* Ph0, const _Float16* Pl0, int S0,
                           const _Float16* Ph1, const _Float16* Pl1, int S1,
                           const _Float16* X0, const _Float16* X1, int C0,
                           const float* bias, const _Float16* res, int Nr,
                           _Float16* out, int No, int O, int C, int N, int relu)
{
    dim3 g(N / 128, O / 64);
    gemm64p_kernel<<<g, 256, 0, st>>>(Ph0, Pl0, S0, Ph1, Pl1, S1, X0, X1,
                                      bias, res, out, O, C, C0, N, Nr, No, relu);
}

extern "C" void kernel_launch(void* const* d_in, const int* in_sizes, int n_in,
                              void* d_out, int out_size, void* d_ws, size_t ws_size,
                              hipStream_t stream)
{
    (void)in_sizes; (void)n_in; (void)out_size; (void)ws_size;
    const float* det_in = (const float*)d_in[0];
    const float* trk_in = (const float*)d_in[1];
    const float* enc_w1 = (const float*)d_in[2];
    const float* enc_b1 = (const float*)d_in[3];
    const float* enc_w2 = (const float*)d_in[4];
    const float* enc_b2 = (const float*)d_in[5];
    const float* fus_pw = (const float*)d_in[6];
    const float* fus_pb = (const float*)d_in[7];
    const float* fus_mw = (const float*)d_in[8];
    const float* fus_mb = (const float*)d_in[9];
    const float* fus_m1w = (const float*)d_in[10];
    const float* fus_m1b = (const float*)d_in[11];
    const float* fus_m2w = (const float*)d_in[12];
    const float* fus_m2b = (const float*)d_in[13];
    const float* gnn_pw = (const float*)d_in[14];
    const float* gnn_pb = (const float*)d_in[15];
    const float* gnn_mw = (const float*)d_in[16];
    const float* gnn_mb = (const float*)d_in[17];
    const float* gnn_m1w = (const float*)d_in[18];
    const float* gnn_m1b = (const float*)d_in[19];
    const float* gnn_m2w = (const float*)d_in[20];
    const float* gnn_m2b = (const float*)d_in[21];
    const float* final_w = (const float*)d_in[22];
    const float* final_b = (const float*)d_in[23];
    const float* bin_sc  = (const float*)d_in[24];
    float* out = (float*)d_out;

    float* ws = (float*)d_ws;
    // fp16 activation buffers (offsets in FLOAT slots from ws; halves = 2x):
    _Float16* XF16  = (_Float16*)ws;                   // [256][NCT] halves
    float* R    = ws + 4194304;            // 16,777,216-float temp arena
    float* COMBf = ws + 20971520;
    _Float16* COMB16 = (_Float16*)COMBf;               // [256][NCB] halves
    float* Z0   = ws + 22282240;           // 1,053,700
    float* U    = ws + 23335940;
    float* V    = ws + 23336968;
    // fuser arena (halves, within R): QKVf [768][NCT] at R; m1-out overlays
    // dead K/V rows; MS at R+12,582,912 floats.
    _Float16* Qf16 = (_Float16*)R;
    _Float16* Kf16 = Qf16 + (size_t)256 * NCT;         // K rows / m1 out [512][NCT]
    _Float16* Vf16 = Qf16 + (size_t)512 * NCT;         // V rows
    _Float16* MS16 = (_Float16*)(R + 12582912);        // [256][NCT]
    // GNN arena (halves): QKV at R; H after QKV; MSG/M at old float offsets.
    _Float16* QKV16 = (_Float16*)R;                    // [768][NCB]
    _Float16* H16   = (_Float16*)(R + 1310720);        // [512][NCB] (after QKV Q rows; QKV dead at use)
    _Float16* MSG16 = (_Float16*)(R + 3932160);        // [256][NCB]
    _Float16* M16   = (_Float16*)(R + 5242880);        // [256][NCB]; det-PE / final proj
    // attn split-K partials (GNN loop only; overlays M which is dead there):
    _Float16* PO = (_Float16*)(R + 5242880);  // [320*4][64][64] halves
    float* PM = R + 7864320;                  // [320*4][64]
    float* PL = R + 7946240;                  // ends 8,028,160 < 8,388,608
    // fused msg-proj weights (fuser): fp16 planes in COMB region
    _Float16* Whff = (_Float16*)COMBf;             // [4][512][256]
    _Float16* Wlff = (_Float16*)(COMBf + 262144);
    float* bcf = COMBf + 524288;                   // [4][512]
    // GNN plane arena: R+8,388,608 floats onward (written after fuser)
    _Float16* GP   = (_Float16*)(R + 8388608);
    _Float16* gph  = GP;
    _Float16* gpl  = GP + 2359296;
    _Float16* gm1h = GP + 4718592;
    _Float16* gm1l = GP + 6291456;
    _Float16* gm2h = GP + 7864320;
    _Float16* gm2l = GP + 9437184;
    _Float16* wfh  = GP + 11010048;
    _Float16* wfl  = GP + 12582912;
    _Float16* fnh  = GP + 14155776;
    _Float16* fnl  = GP + 14221312;      // ends 14,286,848 halves
    float* bcg = R + 15600000;           // [12][512]
    float* Z0T = R;                      // sinkhorn transpose (end phase)
    // fp16 hi/lo weight-plane arena (fuser path), in HALVES from base:
    _Float16* PB = (_Float16*)(ws + 23400000);
    _Float16* e1h = PB;              _Float16* e1l = PB + 65536;
    _Float16* e2h = PB + 131072;     _Float16* e2l = PB + 196608;
    _Float16* pwh = PB + 262144;     _Float16* pwl = PB + 1048576;
    _Float16* m1h = PB + 1835008;    _Float16* m1l = PB + 2883584;
    _Float16* m2h = PB + 3932160;    _Float16* m2l = PB + 4456448;

    // ===== weight-plane precompute =====
    split_multi_kernel<<<9728, 256, 0, stream>>>(
        enc_w1, e1h, e1l, 256, 0,
        enc_w2, e2h, e2l, 512, 0,
        fus_pw, pwh, pwl, 3584, 0,
        fus_m1w, m1h, m1l, 7680, 0,
        fus_m2w, m2h, m2l, 9728, 0);
    fusewh_kernel<<<dim3(2, 8, 4), 256, 0, stream>>>(fus_m1w, fus_mw, Whff, Wlff);
    fusebias_kernel<<<dim3(2, 4), 256, 0, stream>>>(fus_m1w, fus_mb, fus_m1b, bcf);

    // ================= encoder (tracks) + fuser ===========================
    pe_kernel<<<dim3(NCT/256, 4), 256, 0, stream>>>(trk_in, MS16, NCT, 4, 257*16);
    repack_kernel<<<dim3(NCT/256, 256), 256, 0, stream>>>(trk_in, Qf16, NCT, 4, 257*16);
    gemmP64(stream, e1h, e1l, 256, e1h, e1l, 256, Qf16, Qf16, 256,
            enc_b1, nullptr, 0, Kf16, NCT, 256, 256, NCT, 1);
    gemmP64(stream, e2h, e2l, 256, e2h, e2l, 256, Kf16, Kf16, 256,
            enc_b2, MS16, NCT, XF16, NCT, 256, 256, NCT, 0);

    for (int l = 0; l < 4; ++l) {
        gemmP64(stream, pwh + l*196608, pwl + l*196608, 256,
                pwh, pwl, 256, XF16, XF16, 256,
                fus_pb + l*768, nullptr, 0, Qf16, NCT, 768, 256, NCT, 0);
        fuser_attn_kernel<<<1024, 256, 0, stream>>>(Qf16, Kf16, Vf16, MS16);
        gemmP64(stream, m1h + l*262144, m1l + l*262144, 512,
                Whff + l*131072, Wlff + l*131072, 256, XF16, MS16, 256,
                bcf + l*512, nullptr, 0, Kf16, NCT, 512, 512, NCT, 1);
        gemmP64(stream, m2h + l*131072, m2l + l*131072, 512,
                m2h, m2l, 512, Kf16, Kf16, 512,
                fus_m2b + l*256, XF16, NCT, XF16, NCT, 256, 512, NCT, 0);
    }

    // ===== GNN plane precompute (old fuser region now free) ===============
    split_multi_kernel<<<21760, 256, 0, stream>>>(
        gnn_pw, gph, gpl, 9216, 0,
        gnn_m1w, gm1h, gm1l, 15360, 512,
        gnn_m2w, gm2h, gm2l, 21504, 0,
        final_w, fnh, fnl, 21760, 0,
        final_w, fnh, fnl, 21760, 0);
    fusewh_kernel<<<dim3(2, 8, 12), 256, 0, stream>>>(gnn_m1w, gnn_mw, wfh, wfl);
    fusebias_kernel<<<dim3(2, 12), 256, 0, stream>>>(gnn_m1w, gnn_mb, gnn_m1b, bcg);

    meanpool_kernel<<<dim3(4, 256), 256, 0, stream>>>(XF16, COMB16);   // tr cols [0,1024)

    // ================= encoder (detections) -> COMB cols [1024,5120) ======
    pe_kernel<<<dim3(NCD/256, 4), 256, 0, stream>>>(det_in, M16, NCD, 10, 257*1024);
    repack_kernel<<<dim3(NCD/256, 256), 256, 0, stream>>>(det_in, Qf16, NCD, 10, 257*1024);
    gemmP64(stream, e1h, e1l, 256, e1h, e1l, 256, Qf16, Qf16, 256,
            enc_b1, nullptr, 0, Kf16, NCD, 256, 256, NCD, 1);
    gemmP64(stream, e2h, e2l, 256, e2h, e2l, 256, Kf16, Kf16, 256,
            enc_b2, M16, NCD, COMB16 + 1024, NCB, 256, 256, NCD, 0);

    // ================= GNN (combined tr|det, N=5120) ======================
    for (int l = 0; l < 12; ++l) {
        const _Float16* lph = gph + l*196608;
        const _Float16* lpl = gpl + l*196608;
        const float* pb  = gnn_pb + l*768;
        const float* m2b = gnn_m2b + l*256;
        const int cross = (l & 1);

        gemmP64(stream, lph, lpl, 256, lph, lpl, 256, COMB16, COMB16, 256,
                pb, nullptr, 0, QKV16, NCB, 768, 256, NCB, 0);
        attn2_kernel<<<dim3(80, 4, 4), 256, 0, stream>>>(QKV16, PO, PM, PL, cross);
        attn_merge_kernel<<<dim3(20, 4, 4), 256, 0, stream>>>(PO, PM, PL, MSG16);
        gemmP64(stream, gm1h + l*131072, gm1l + l*131072, 256,
                wfh + l*131072, wfl + l*131072, 256, COMB16, MSG16, 256,
                bcg + l*512, nullptr, 0, H16, NCB, 512, 512, NCB, 1);
        gemmP64(stream, gm2h + l*131072, gm2l + l*131072, 512,
                gm2h + l*131072, gm2l + l*131072, 512, H16, H16, 512,
                m2b, COMB16, NCB, COMB16, NCB, 256, 512, NCB, 0);
    }

    // ================= final projection + scores + sinkhorn ===============
    gemmP64(stream, fnh, fnl, 256, fnh, fnl, 256, COMB16, COMB16, 256,
            final_b, nullptr, 0, M16, NCB, 256, 256, NCB, 0);
    scores_kernel<<<dim3(16, 4, 4), 256, 0, stream>>>(M16, Z0, Z0T);
    sink_init_kernel<<<21, 256, 0, stream>>>(Z0, Z0T, V, bin_sc);
    for (int it = 0; it < SINK_IT; ++it) {
        sink_u_kernel<<<257, 256, 0, stream>>>(Z0, V, U);
        sink_v_kernel<<<1025, 256, 0, stream>>>(Z0T, U, V);
    }
    sink_out_kernel<<<dim3(5, 257, 4), 256, 0, stream>>>(Z0, U, V, out);
}